// Round 14
// baseline (598.855 us; speedup 1.0000x reference)
//
#include <hip/hip_runtime.h>
#include <math.h>

#define BB 4
#define CI 6
#define LL 4096
#define DMC 72
#define DIC 144
#define KD 4
#define NS 8
#define RD 4
#define NLAYER 2
#define GRP 12
#define NCH 256   // chunks per scan
#define TS 16     // steps per chunk
#define SP 72     // padded row stride (left pad 4 -> 4-elem aligned interior)
#define PPN (66*SP)
#define L2E 1.4426950408889634f

__device__ __forceinline__ float sigmoidf_(float x){ return 1.f/(1.f+__expf(-x)); }
__device__ __forceinline__ float siluf_(float x){ return x*sigmoidf_(x); }
__device__ __forceinline__ float softplusf_(float x){
  return fmaxf(x,0.f) + __logf(1.f + __expf(-fabsf(x)));
}

__device__ __forceinline__ int padidx(int p){ return SP*(p>>6) + (p&63) + SP + 4; }

#define LOAD9(ip, a) do { \
  a[0]=(ip)[-SP-1]; a[1]=(ip)[-SP]; a[2]=(ip)[-SP+1]; \
  a[3]=(ip)[-1];    a[4]=(ip)[0];   a[5]=(ip)[1];     \
  a[6]=(ip)[SP-1];  a[7]=(ip)[SP];  a[8]=(ip)[SP+1];  } while(0)

// 6 contiguous values (cols -1..4), base 4-elem aligned
__device__ __forceinline__ void load6(const float* __restrict__ base, float v[6]){
  v[0] = base[-1];
  float4 f = *(const float4*)base;
  v[1]=f.x; v[2]=f.y; v[3]=f.z; v[4]=f.w;
  v[5] = base[4];
}

// ---------- zero halos of all padded planes ----------
__global__ void k_halo(float* __restrict__ pads, int nplanes){
  int plane = blockIdx.x;
  if (plane >= nplanes) return;
  int t = threadIdx.x;
  if (t >= 260) return;
  float* pl = pads + (size_t)plane*PPN;
  int row, col;
  if (t < 132){
    row = (t < 66) ? 0 : 65;
    col = 3 + (t % 66);
  } else {
    int j = t - 132;
    col = (j < 64) ? 3 : 68;
    row = 1 + (j & 63);
  }
  pl[row*SP + col] = 0.f;
}

// ---------- pad copy of the input image ----------
__global__ void k_pad_img(const float* __restrict__ img, float* __restrict__ img_pad){
  int idx = blockIdx.x*256 + threadIdx.x;
  if (idx >= BB*CI*LL) return;
  int p = idx & 4095; int bc = idx >> 12;
  img_pad[(size_t)bc*PPN + padidx(p)] = img[idx];
}

// ---------- conv 6->72 3x3 + lrelu(0.01); 4 px/thread ----------
__global__ void k_conv1(const float* __restrict__ img_pad, const float* __restrict__ w,
                        const float* __restrict__ bias, float* __restrict__ tmp_pad){
  int bid = blockIdx.x;
  int tile = bid & 3; int r = bid >> 2; int o = r % DMC; int b = r / DMC;
  int p0 = tile*1024 + threadIdx.x*4;
  int pb = padidx(p0);
  float bv = bias[o];
  float acc[4] = {bv,bv,bv,bv};
  #pragma unroll
  for (int ic=0; ic<CI; ++ic){
    const float* ip = img_pad + (size_t)(b*CI+ic)*PPN + pb;
    const float* wr = w + (o*CI+ic)*9;
    #pragma unroll
    for (int rr=0; rr<3; ++rr){
      float v[6]; load6(ip + (rr-1)*SP, v);
      float w0=wr[rr*3], w1=wr[rr*3+1], w2v=wr[rr*3+2];
      #pragma unroll
      for (int q=0;q<4;++q) acc[q] += v[q]*w0 + v[q+1]*w1 + v[q+2]*w2v;
    }
  }
  #pragma unroll
  for (int q=0;q<4;++q) acc[q] = acc[q] >= 0.f ? acc[q] : 0.01f*acc[q];
  *(float4*)(tmp_pad + (size_t)(b*DMC+o)*PPN + pb) = make_float4(acc[0],acc[1],acc[2],acc[3]);
}

// ---------- conv2 init: bias + 1x1 shortcut -> x ----------
__global__ void k_conv2init(const float* __restrict__ img, const float* __restrict__ b2,
                            const float* __restrict__ wsc, const float* __restrict__ bsc,
                            float* __restrict__ xout){
  int bid = blockIdx.x;
  int t = bid & 15; int r = bid >> 4; int og = r % 18; int b = r / 18;
  int p = t*256 + threadIdx.x;
  float acc[4];
  #pragma unroll
  for (int j=0;j<4;++j) acc[j] = b2[og*4+j] + bsc[og*4+j];
  #pragma unroll
  for (int ic=0; ic<CI; ++ic){
    float v = img[((b*CI+ic)<<12)+p];
    #pragma unroll
    for (int j=0;j<4;++j) acc[j] += v * wsc[(og*4+j)*CI+ic];
  }
  #pragma unroll
  for (int j=0;j<4;++j)
    xout[((b*DMC+og*4+j)<<12)+p] = acc[j];
}

// ---------- conv2: 3x3 partials; 1 px x 4 oc /thread; ic-split x2; coalesced atomics ----------
__global__ void k_conv2(const float* __restrict__ tmp_pad,
                        const float* __restrict__ w2, float* __restrict__ xout){
  int bid = blockIdx.x;
  int t = bid & 15; int r = bid >> 4; int og = r % 18; r /= 18;
  int icg = r & 1; int b = r >> 1;
  int p = t*256 + threadIdx.x;
  int pb = padidx(p);
  float acc[4] = {0.f,0.f,0.f,0.f};
  const float* ipb = tmp_pad + (size_t)b*DMC*PPN + pb;
  const float* wb  = w2 + (size_t)(og*4)*DMC*9;
  #pragma unroll 2
  for (int ii=0; ii<36; ++ii){
    int ic = icg*36 + ii;
    const float* ip = ipb + (size_t)ic*PPN;
    float a[9]; LOAD9(ip, a);
    const float* wp = wb + ic*9;
    #pragma unroll
    for (int j=0;j<4;++j){
      float s = 0.f;
      #pragma unroll
      for (int q=0;q<9;++q) s += a[q]*wp[(size_t)j*DMC*9 + q];
      acc[j] += s;
    }
  }
  #pragma unroll
  for (int j=0;j<4;++j)
    atomicAdd(xout + ((b*DMC+og*4+j)<<12)+p, acc[j]);
}

// ---------- xz: 144 ch -> padded planes; z -> z_t [b][p][c] ----------
__global__ void k_xz(const float* __restrict__ x, const float* __restrict__ inw,
                     float* __restrict__ xz_pad, float* __restrict__ z_t, int relu){
  int bid = blockIdx.x;
  int t = bid & 15; int r = bid >> 4; int eg = r % 36; int b = r / 36;
  int p = t*256 + threadIdx.x;
  float acc[8] = {0.f,0.f,0.f,0.f,0.f,0.f,0.f,0.f};
  for (int c0=0; c0<DMC; c0+=4){
    float a[4];
    #pragma unroll
    for (int q=0;q<4;++q) a[q] = x[((b*DMC+c0+q)<<12)+p];
    if (relu){
      #pragma unroll
      for (int q=0;q<4;++q) a[q] = a[q] >= 0.f ? a[q] : 0.01f*a[q];
    }
    #pragma unroll
    for (int j=0;j<8;++j){
      float4 w = *(const float4*)(inw + (eg*8+j)*DMC + c0);
      acc[j] += a[0]*w.x + a[1]*w.y + a[2]*w.z + a[3]*w.w;
    }
  }
  if (eg < 18){
    int pb = padidx(p);
    #pragma unroll
    for (int j=0;j<8;++j) xz_pad[(size_t)(b*DIC+eg*8+j)*PPN + pb] = acc[j];
  } else {
    float* zb = z_t + ((size_t)b*LL+p)*DIC + (eg*8-DIC);
    *(float4*)(zb)   = make_float4(acc[0],acc[1],acc[2],acc[3]);
    *(float4*)(zb+4) = make_float4(acc[4],acc[5],acc[6],acc[7]);
  }
}

// ---------- depthwise 3x3 + bias + silu; 4 px/thread -> xi_t [b][p][c] ----------
__global__ void k_dw(const float* __restrict__ xz_pad, const float* __restrict__ dww,
                     const float* __restrict__ dwb, float* __restrict__ xi_t){
  int bid = blockIdx.x;
  int tile = bid & 3; int r = bid >> 2; int c = r % DIC; int b = r / DIC;
  int p0 = tile*1024 + threadIdx.x*4;
  int pb = padidx(p0);
  const float* ip = xz_pad + (size_t)(b*DIC+c)*PPN + pb;
  const float* wp = dww + c*9;
  float bv = dwb[c];
  float acc[4] = {bv,bv,bv,bv};
  #pragma unroll
  for (int rr=0; rr<3; ++rr){
    float v[6]; load6(ip + (rr-1)*SP, v);
    float w0=wp[rr*3], w1=wp[rr*3+1], w2v=wp[rr*3+2];
    #pragma unroll
    for (int q=0;q<4;++q) acc[q] += v[q]*w0 + v[q+1]*w1 + v[q+2]*w2v;
  }
  #pragma unroll
  for (int q=0;q<4;++q)
    xi_t[((size_t)b*LL+p0+q)*DIC + c] = siluf_(acc[q]);
}

// ---------- x_dbl [bk][p][20]; 4 parts of 5 ch ----------
__global__ void k_xdbl(const float* __restrict__ xi_t, const float* __restrict__ xpw,
                       float* __restrict__ xdbl){
  int bid = blockIdx.x;
  int t = bid & 15; int r = bid >> 4;
  int kk = r & 3; r >>= 2; int part = r & 3; int b = r >> 2;
  int p = t*256 + threadIdx.x;
  const float* xib = xi_t + ((size_t)b*LL + p)*DIC;
  const float* wk = xpw + (size_t)(kk*20 + part*5)*DIC;
  float acc[5] = {0.f,0.f,0.f,0.f,0.f};
  for (int d=0; d<DIC; d+=4){
    float4 v = *(const float4*)(xib + d);
    #pragma unroll
    for (int c=0;c<5;++c){
      float4 w = *(const float4*)(wk + (size_t)c*DIC + d);
      acc[c] += v.x*w.x + v.y*w.y + v.z*w.z + v.w*w.w;
    }
  }
  float* dst = xdbl + ((size_t)(b*KD+kk)*LL + p)*20 + part*5;
  #pragma unroll
  for (int c=0;c<5;++c) dst[c] = acc[c];
}

__device__ __forceinline__ void scan_decode(int idx, int& b, int& k, int& ch, int& c){
  c = idx % DIC;
  int r = idx / DIC;
  ch = r % NCH;
  r /= NCH;
  k = r & 3; b = r >> 2;
}

// affine scan-position: ps(t) = ps0 + t*sk within a chunk (no 64-boundary carry: TS=16)
__device__ __forceinline__ void scan_affine(int k, int ch, int& ps0, int& sk){
  int l0 = ch*TS;
  if (k == 0){ ps0 = l0; sk = 1; }
  else if (k == 1){ ps0 = ((l0 & 63) << 6) | (l0 >> 6); sk = 64; }
  else if (k == 2){ ps0 = (LL-1) - l0; sk = -1; }
  else { int m0 = (LL-1) - l0; ps0 = ((m0 & 63) << 6) | (m0 >> 6); sk = -64; }
}

// ---------- P1: local scans; stores hp + cumdt (scalar); zeroes y_t (4 strided stores) ----------
__global__ void k_p1(const float* __restrict__ xi_t, const float* __restrict__ xdbl,
                     const float* __restrict__ dtpw, const float* __restrict__ dtpb,
                     const float* __restrict__ alog,
                     float* __restrict__ cumdt, float* __restrict__ hp,
                     float* __restrict__ y_t){
  int idx = blockIdx.x*256 + threadIdx.x;
  if (idx >= BB*KD*NCH*DIC) return;
  // zero y_t: 4 coalesced strided stores cover BB*LL*DIC = 4 * BB*KD*NCH*DIC
  const int NQ = BB*KD*NCH*DIC;
  #pragma unroll
  for (int j=0;j<4;++j) y_t[idx + (size_t)j*NQ] = 0.f;
  int b,k,ch,c; scan_decode(idx,b,k,ch,c);
  float Arow[NS];
  #pragma unroll
  for (int n=0;n<NS;++n) Arow[n] = -__expf(alog[(k*DIC+c)*NS+n]) * L2E;
  float4 wdt = *(const float4*)(dtpw + (k*DIC+c)*RD);
  float bdt = dtpb[k*DIC+c];
  int ps0, sk; scan_affine(k, ch, ps0, sk);
  const float* row = xdbl + (size_t)(b*KD+k)*LL*20 + (size_t)ps0*20;
  const float* up  = xi_t + (size_t)b*LL*DIC + c + (size_t)ps0*DIC;
  long rstep = (long)sk*20;
  long ustep = (long)sk*DIC;
  float h[NS];
  #pragma unroll
  for (int n=0;n<NS;++n) h[n]=0.f;
  float sumd = 0.f;
  #pragma unroll 4
  for (int t=0; t<TS; ++t){
    float4 q0 = *(const float4*)(row);
    float4 q1 = *(const float4*)(row+4);
    float4 q2 = *(const float4*)(row+8);
    float u = *up;
    float dt = bdt + q0.x*wdt.x + q0.y*wdt.y + q0.z*wdt.z + q0.w*wdt.w;
    dt = softplusf_(dt);
    sumd += dt;
    float du = dt*u;
    float Bv[NS] = {q1.x,q1.y,q1.z,q1.w,q2.x,q2.y,q2.z,q2.w};
    #pragma unroll
    for (int n=0;n<NS;++n)
      h[n] = h[n]*exp2f(dt*Arow[n]) + du*Bv[n];
    row += rstep; up += ustep;
  }
  size_t base = ((size_t)((b*KD+k)*NCH + ch)*NS)*DIC + c;
  #pragma unroll
  for (int n=0;n<NS;++n) hp[base + n*DIC] = h[n];
  cumdt[((size_t)((b*KD+k)*NCH + ch))*DIC + c] = sumd;
}

// ---------- P2: prefix via cumdt; zeroes gnstats ----------
__global__ void k_p2(const float* __restrict__ cumdt, float* __restrict__ hp,
                     const float* __restrict__ alog, float* __restrict__ gnstats){
  if (blockIdx.x == 0 && threadIdx.x < 2*BB*GRP) gnstats[threadIdx.x] = 0.f;
  int idx = blockIdx.x*256 + threadIdx.x;
  if (idx >= BB*KD*NS*DIC) return;
  int c = idx % DIC; int n = (idx/DIC) % NS; int bk = idx/(DIC*NS);
  int k = bk & 3;
  float Arow = -__expf(alog[(k*DIC+c)*NS+n]) * L2E;
  float h = 0.f;
  #pragma unroll 4
  for (int ch=0; ch<NCH; ++ch){
    float sd = cumdt[((size_t)(bk*NCH+ch))*DIC + c];
    float a = exp2f(sd*Arow);
    size_t base = ((size_t)(bk*NCH+ch)*NS + n)*DIC + c;
    float pp = hp[base];
    hp[base] = h;
    h = a*h + pp;
  }
}

// ---------- P3: paired directions (0,2)/(1,3); register y-accumulate; 2 atomics/cell ----------
__global__ void k_p3(const float* __restrict__ xi_t, const float* __restrict__ xdbl,
                     const float* __restrict__ dtpw, const float* __restrict__ dtpb,
                     const float* __restrict__ alog, const float* __restrict__ Dsv,
                     const float* __restrict__ hin, float* __restrict__ y_t){
  int idx = blockIdx.x*256 + threadIdx.x;
  if (idx >= BB*2*NCH*DIC) return;
  int c = idx % DIC;
  int r = idx / DIC;
  int ch = r % NCH; r /= NCH;
  int pr = r & 1; int b = r >> 1;
  int kA = pr, kB = pr | 2;
  int chB = NCH-1-ch;
  int st = pr ? 64 : 1;
  int l0 = ch*TS;
  int p0 = pr ? (((l0 & 63) << 6) | (l0 >> 6)) : l0;

  float ArowA[NS], ArowB[NS];
  #pragma unroll
  for (int n=0;n<NS;++n){
    ArowA[n] = -__expf(alog[(kA*DIC+c)*NS+n]) * L2E;
    ArowB[n] = -__expf(alog[(kB*DIC+c)*NS+n]) * L2E;
  }
  float4 wdtA = *(const float4*)(dtpw + (kA*DIC+c)*RD);
  float4 wdtB = *(const float4*)(dtpw + (kB*DIC+c)*RD);
  float bdtA = dtpb[kA*DIC+c];
  float bdtB = dtpb[kB*DIC+c];
  float Dsum = Dsv[kA*DIC+c] + Dsv[kB*DIC+c];
  const float* xdA = xdbl + (size_t)(b*KD+kA)*LL*20;
  const float* xdB = xdbl + (size_t)(b*KD+kB)*LL*20;
  const float* up = xi_t + (size_t)b*LL*DIC + c;
  float* yb = y_t + (size_t)b*LL*DIC + c;
  float hA[NS], hB[NS];
  size_t baseA = ((size_t)((b*KD+kA)*NCH + ch)*NS)*DIC + c;
  size_t baseB = ((size_t)((b*KD+kB)*NCH + chB)*NS)*DIC + c;
  #pragma unroll
  for (int n=0;n<NS;++n){ hA[n] = hin[baseA + n*DIC]; hB[n] = hin[baseB + n*DIC]; }
  float yacc[TS];
  #pragma unroll
  for (int j=0;j<TS;++j) yacc[j] = 0.f;

  #pragma unroll
  for (int t=0; t<TS; ++t){
    int pA = p0 + t*st;
    int pB = p0 + (TS-1-t)*st;
    // direction A (forward over positions)
    {
      const float* row = xdA + (size_t)pA*20;
      float4 q0 = *(const float4*)(row);
      float4 q1 = *(const float4*)(row+4);
      float4 q2 = *(const float4*)(row+8);
      float4 q3 = *(const float4*)(row+12);
      float4 q4 = *(const float4*)(row+16);
      float u = up[(size_t)pA*DIC];
      float dt = bdtA + q0.x*wdtA.x + q0.y*wdtA.y + q0.z*wdtA.z + q0.w*wdtA.w;
      dt = softplusf_(dt);
      float du = dt*u;
      float Bv[NS] = {q1.x,q1.y,q1.z,q1.w,q2.x,q2.y,q2.z,q2.w};
      float Cv[NS] = {q3.x,q3.y,q3.z,q3.w,q4.x,q4.y,q4.z,q4.w};
      float y = 0.f;
      #pragma unroll
      for (int n=0;n<NS;++n){
        hA[n] = hA[n]*exp2f(dt*ArowA[n]) + du*Bv[n];
        y += hA[n]*Cv[n];
      }
      yacc[t] += y + u*Dsum;
    }
    // direction B (backward over positions)
    {
      const float* row = xdB + (size_t)pB*20;
      float4 q0 = *(const float4*)(row);
      float4 q1 = *(const float4*)(row+4);
      float4 q2 = *(const float4*)(row+8);
      float4 q3 = *(const float4*)(row+12);
      float4 q4 = *(const float4*)(row+16);
      float u = up[(size_t)pB*DIC];
      float dt = bdtB + q0.x*wdtB.x + q0.y*wdtB.y + q0.z*wdtB.z + q0.w*wdtB.w;
      dt = softplusf_(dt);
      float du = dt*u;
      float Bv[NS] = {q1.x,q1.y,q1.z,q1.w,q2.x,q2.y,q2.z,q2.w};
      float Cv[NS] = {q3.x,q3.y,q3.z,q3.w,q4.x,q4.y,q4.z,q4.w};
      float y = 0.f;
      #pragma unroll
      for (int n=0;n<NS;++n){
        hB[n] = hB[n]*exp2f(dt*ArowB[n]) + du*Bv[n];
        y += hB[n]*Cv[n];
      }
      yacc[TS-1-t] += y;
    }
  }
  #pragma unroll
  for (int j=0;j<TS;++j)
    atomicAdd(yb + (size_t)(p0 + j*st)*DIC, yacc[j]);
}

// ---------- LN over c per pixel (wave-per-pixel), *ong+onb, *silu(z); also zeroes x ----------
__global__ void k_lnz(float* __restrict__ y_t, const float* __restrict__ z_t,
                      const float* __restrict__ ong, const float* __restrict__ onb,
                      float* __restrict__ xzero){
  int gid = blockIdx.x*256 + threadIdx.x;
  // zero x (dead between xz and oproj) for oproj's atomic partials
  xzero[gid] = 0.f;
  if (gid < (int)(BB*DMC*LL - BB*LL*64)) xzero[gid + BB*LL*64] = 0.f;
  int wid = gid >> 6;
  int lane = gid & 63;
  if (wid >= BB*LL) return;
  size_t rb = (size_t)wid * DIC;
  float v0 = y_t[rb + lane];
  float v1 = y_t[rb + 64 + lane];
  float v2 = (lane < 16) ? y_t[rb + 128 + lane] : 0.f;
  float s = v0 + v1 + v2;
  float q = v0*v0 + v1*v1 + v2*v2;
  #pragma unroll
  for (int o=32; o>0; o>>=1){ s += __shfl_xor(s,o,64); q += __shfl_xor(q,o,64); }
  float mu = s*(1.f/DIC);
  float var = q*(1.f/DIC) - mu*mu;
  float rs = rsqrtf(var + 1e-5f);
  float z0 = z_t[rb + lane];
  y_t[rb + lane] = ((v0-mu)*rs*ong[lane] + onb[lane]) * siluf_(z0);
  float z1 = z_t[rb + 64 + lane];
  y_t[rb + 64 + lane] = ((v1-mu)*rs*ong[64+lane] + onb[64+lane]) * siluf_(z1);
  if (lane < 16){
    float z2 = z_t[rb + 128 + lane];
    y_t[rb + 128 + lane] = ((v2-mu)*rs*ong[128+lane] + onb[128+lane]) * siluf_(z2);
  }
}

// ---------- out-proj matmul, LDS-staged, d-split x2, atomic partials into x ----------
__global__ void k_oproj(const float* __restrict__ yn, const float* __restrict__ opw,
                        float* __restrict__ xout){
  __shared__ float ly[72*65];
  int bid = blockIdx.x;            // BB * 64 tiles * 2 dhalves
  int dhalf = bid & 1; int r = bid >> 1;
  int tile = r & 63; int b = r >> 6;
  int pstart = tile*64;
  const float* src = yn + ((size_t)b*LL + pstart)*DIC + dhalf*72;
  for (int i = threadIdx.x; i < 64*72; i += 512){
    int px = i / 72; int d = i - px*72;
    ly[d*65 + px] = src[(size_t)px*DIC + d];
  }
  __syncthreads();
  int px = threadIdx.x & 63;
  int ocg = __builtin_amdgcn_readfirstlane(threadIdx.x >> 6);  // 0..7 wave-uniform
  float acc[9];
  #pragma unroll
  for (int j=0;j<9;++j) acc[j]=0.f;
  const float* wb = opw + (size_t)ocg*9*DIC + dhalf*72;
  #pragma unroll 4
  for (int d=0; d<72; ++d){
    float a = ly[d*65 + px];
    #pragma unroll
    for (int j=0;j<9;++j) acc[j] += a * wb[(size_t)j*DIC + d];
  }
  #pragma unroll
  for (int j=0;j<9;++j)
    atomicAdd(xout + ((size_t)(b*DMC + ocg*9 + j)<<12) + pstart + px, acc[j]);
}

// ---------- groupnorm stats: partial sums -> atomic (sum, sumsq) per (b,group) ----------
__global__ void k_gnA(const float* __restrict__ x, float* __restrict__ stats){
  __shared__ float s1[256], s2[256];
  int bid = blockIdx.x;    // BB*GRP*16
  int t = bid & 15; int r = bid >> 4; int gr = r % GRP; int b = r / GRP;
  float ls=0.f, lq=0.f;
  #pragma unroll
  for (int it=0; it<6; ++it){
    int i = t*1536 + it*256 + threadIdx.x;   // i in [0, 24576)
    int c = gr*6 + (i>>12); int p = i & 4095;
    float v = x[((size_t)(b*DMC+c)<<12)+p];
    ls += v; lq += v*v;
  }
  s1[threadIdx.x]=ls; s2[threadIdx.x]=lq; __syncthreads();
  for (int s=128; s>0; s>>=1){
    if (threadIdx.x < s){ s1[threadIdx.x]+=s1[threadIdx.x+s]; s2[threadIdx.x]+=s2[threadIdx.x+s]; }
    __syncthreads();
  }
  if (threadIdx.x == 0){
    atomicAdd(stats + (b*GRP+gr)*2,     s1[0]);
    atomicAdd(stats + (b*GRP+gr)*2 + 1, s2[0]);
  }
}

// ---------- dense1: l1( gn(x) ), GN A/B computed in-block ----------
__global__ void k_dense1(const float* __restrict__ xin, const float* __restrict__ gnstats,
                         const float* __restrict__ gng, const float* __restrict__ gnb,
                         const float* __restrict__ w, const float* __restrict__ bias,
                         float* __restrict__ xout){
  __shared__ float As[DMC], Bs[DMC];
  int bid = blockIdx.x;
  int t = bid & 15; int r = bid >> 4; int eg = r % 18; int b = r / 18;
  if (threadIdx.x < DMC){
    int c = threadIdx.x; int gr = c/6;
    float s = gnstats[(b*GRP+gr)*2];
    float q = gnstats[(b*GRP+gr)*2 + 1];
    const float inv = 1.f/(6.f*LL);
    float mu = s*inv;
    float var = q*inv - mu*mu;
    float rs = rsqrtf(var + 1e-5f);
    float A = rs*gng[c];
    As[c] = A;
    Bs[c] = gnb[c] - mu*A;
  }
  __syncthreads();
  int p = t*256 + threadIdx.x;
  float acc[4];
  #pragma unroll
  for (int j=0;j<4;++j) acc[j] = bias[eg*4+j];
  for (int c0=0; c0<DMC; c0+=4){
    float a[4];
    #pragma unroll
    for (int q=0;q<4;++q){
      float v = xin[((size_t)(b*DMC+c0+q)<<12)+p];
      a[q] = v*As[c0+q] + Bs[c0+q];
    }
    #pragma unroll
    for (int j=0;j<4;++j){
      float4 w0 = *(const float4*)(w + (eg*4+j)*DMC + c0);
      acc[j] += a[0]*w0.x + a[1]*w0.y + a[2]*w0.z + a[3]*w0.w;
    }
  }
  #pragma unroll
  for (int j=0;j<4;++j)
    xout[((size_t)(b*DMC+eg*4+j)<<12)+p] = acc[j];
}

// ---------- dense2: l2( lrelu(tmp) ) ----------
__global__ void k_dense2(const float* __restrict__ xin, const float* __restrict__ w,
                         const float* __restrict__ bias, float* __restrict__ xout,
                         float* __restrict__ pad_out){
  int bid = blockIdx.x;
  int t = bid & 15; int r = bid >> 4; int eg = r % 18; int b = r / 18;
  int p = t*256 + threadIdx.x;
  float acc[4];
  #pragma unroll
  for (int j=0;j<4;++j) acc[j] = bias[eg*4+j];
  for (int c0=0; c0<DMC; c0+=4){
    float a[4];
    #pragma unroll
    for (int q=0;q<4;++q){
      float v = xin[((size_t)(b*DMC+c0+q)<<12)+p];
      a[q] = v >= 0.f ? v : 0.04f*v;
    }
    #pragma unroll
    for (int j=0;j<4;++j){
      float4 w0 = *(const float4*)(w + (eg*4+j)*DMC + c0);
      acc[j] += a[0]*w0.x + a[1]*w0.y + a[2]*w0.z + a[3]*w0.w;
    }
  }
  int pb = padidx(p);
  #pragma unroll
  for (int j=0;j<4;++j){
    xout[((size_t)(b*DMC+eg*4+j)<<12)+p] = acc[j];
    if (pad_out) pad_out[(size_t)(b*DMC+eg*4+j)*PPN + pb] = acc[j];
  }
}

// ---------- shrink conv pass A ----------
__global__ void k_shrinkA(const float* __restrict__ x_pad, const float* __restrict__ w,
                          float* __restrict__ pacc){
  int bid = blockIdx.x;
  int t = bid & 15; int r = bid >> 4; int icg = r % 24; int b = r / 24;
  int p = t*256 + threadIdx.x;
  int pb = padidx(p);
  float acc[6] = {0.f,0.f,0.f,0.f,0.f,0.f};
  const float* ipb = x_pad + (size_t)b*DMC*PPN + pb;
  #pragma unroll
  for (int ii=0; ii<3; ++ii){
    int ic = icg*3 + ii;
    const float* ip = ipb + (size_t)ic*PPN;
    float a[9]; LOAD9(ip, a);
    #pragma unroll
    for (int o=0;o<6;++o){
      const float* wp = w + (o*DMC+ic)*9;
      float s = 0.f;
      #pragma unroll
      for (int q=0;q<9;++q) s += a[q]*wp[q];
      acc[o] += s;
    }
  }
  #pragma unroll
  for (int o=0;o<6;++o)
    atomicAdd(pacc + ((size_t)(b*CI+o)<<12)+p, acc[o]);
}

// ---------- shrink pass B ----------
__global__ void k_sig(const float* __restrict__ pacc, const float* __restrict__ bias,
                      float* __restrict__ out){
  int idx = blockIdx.x*256 + threadIdx.x;
  if (idx >= BB*CI*LL) return;
  int o = (idx>>12) % CI;
  out[idx] = sigmoidf_(pacc[idx] + bias[o]);
}

extern "C" void kernel_launch(void* const* d_in, const int* in_sizes, int n_in,
                              void* d_out, int out_size, void* d_ws, size_t ws_size,
                              hipStream_t stream){
  const float* image = (const float*)d_in[0];
  const float* cb_w1 = (const float*)d_in[1];
  const float* cb_b1 = (const float*)d_in[2];
  const float* cb_w2 = (const float*)d_in[3];
  const float* cb_b2 = (const float*)d_in[4];
  const float* cb_ws = (const float*)d_in[5];
  const float* cb_bs = (const float*)d_in[6];
  const float* in_w  = (const float*)d_in[7];
  const float* dw_w  = (const float*)d_in[8];
  const float* dw_b  = (const float*)d_in[9];
  const float* xp_w  = (const float*)d_in[10];
  const float* dtp_w = (const float*)d_in[11];
  const float* dtp_b = (const float*)d_in[12];
  const float* A_logs= (const float*)d_in[13];
  const float* Ds    = (const float*)d_in[14];
  const float* ong   = (const float*)d_in[15];
  const float* onb   = (const float*)d_in[16];
  const float* op_w  = (const float*)d_in[17];
  const float* gn_g  = (const float*)d_in[18];
  const float* gn_b  = (const float*)d_in[19];
  const float* l1_w  = (const float*)d_in[20];
  const float* l1_b  = (const float*)d_in[21];
  const float* l2_w  = (const float*)d_in[22];
  const float* l2_b  = (const float*)d_in[23];
  const float* sh_w  = (const float*)d_in[24];
  const float* sh_b  = (const float*)d_in[25];

  const size_t SZ_X  = (size_t)BB*DMC*LL;
  const size_t SZ_C  = (size_t)BB*DIC*LL;
  const size_t SZ_XD = (size_t)BB*KD*20*LL;
  const size_t SZ_CD = (size_t)BB*KD*NCH*DIC;    // cumdt
  const size_t SZ_HP = (size_t)BB*KD*NCH*NS*DIC;
  const size_t SZ_IP = (size_t)BB*CI*PPN;
  const size_t SZ_TP = (size_t)BB*DMC*PPN;
  const size_t SZ_ZP = (size_t)BB*DIC*PPN;

  float* ws = (float*)d_ws;
  size_t off = 0;
  float* x     = ws + off; off += SZ_X;
  float* tmp   = ws + off; off += SZ_X;
  float* z_t   = ws + off; off += SZ_C;
  float* xi_t  = ws + off; off += SZ_C;
  float* xdbl  = ws + off; off += SZ_XD;
  float* y_t   = ws + off; off += SZ_C;
  float* cumdt = ws + off; off += SZ_CD;
  float* hp    = ws + off; off += SZ_HP;
  float* pads  = ws + off;
  float* img_pad = pads;
  float* tmp_pad = img_pad + SZ_IP;
  float* xz_pad  = tmp_pad + SZ_TP;
  off += SZ_IP + SZ_TP + SZ_ZP;
  float* gnstats = ws + off; off += 2*BB*GRP;
  if (ws_size < off*sizeof(float)) return;

  dim3 blk(256);
  const int NPLANES = BB*CI + BB*DMC + BB*DIC;

  k_halo<<<dim3(NPLANES), blk, 0, stream>>>(pads, NPLANES);
  k_pad_img<<<dim3(BB*CI*16), blk, 0, stream>>>(image, img_pad);
  k_conv1<<<dim3(BB*DMC*4), blk, 0, stream>>>(img_pad, cb_w1, cb_b1, tmp_pad);
  k_conv2init<<<dim3(BB*18*16), blk, 0, stream>>>(image, cb_b2, cb_ws, cb_bs, x);
  k_conv2<<<dim3(BB*2*18*16), blk, 0, stream>>>(tmp_pad, cb_w2, x);

  for (int i=0; i<NLAYER; ++i){
    const float* in_w_i  = in_w  + (size_t)i*2*DIC*DMC;
    const float* dw_w_i  = dw_w  + (size_t)i*DIC*9;
    const float* dw_b_i  = dw_b  + (size_t)i*DIC;
    const float* xp_w_i  = xp_w  + (size_t)i*KD*20*DIC;
    const float* dtp_w_i = dtp_w + (size_t)i*KD*DIC*RD;
    const float* dtp_b_i = dtp_b + (size_t)i*KD*DIC;
    const float* alog_i  = A_logs+ (size_t)i*KD*DIC*NS;
    const float* Ds_i    = Ds    + (size_t)i*KD*DIC;
    const float* ong_i   = ong   + (size_t)i*DIC;
    const float* onb_i   = onb   + (size_t)i*DIC;
    const float* op_w_i  = op_w  + (size_t)i*DMC*DIC;
    const float* gn_g_i  = gn_g  + (size_t)i*DMC;
    const float* gn_b_i  = gn_b  + (size_t)i*DMC;
    const float* l1_w_i  = l1_w  + (size_t)i*DMC*DMC;
    const float* l1_b_i  = l1_b  + (size_t)i*DMC;
    const float* l2_w_i  = l2_w  + (size_t)i*DMC*DMC;
    const float* l2_b_i  = l2_b  + (size_t)i*DMC;

    k_xz  <<<dim3(BB*36*16), blk, 0, stream>>>(x, in_w_i, xz_pad, z_t, (i==0)?1:0);
    k_dw  <<<dim3(BB*DIC*4), blk, 0, stream>>>(xz_pad, dw_w_i, dw_b_i, xi_t);
    k_xdbl<<<dim3(BB*4*KD*16), blk, 0, stream>>>(xi_t, xp_w_i, xdbl);
    k_p1  <<<dim3(BB*KD*NCH*DIC/256), blk, 0, stream>>>(xi_t, xdbl, dtp_w_i, dtp_b_i, alog_i, cumdt, hp, y_t);
    k_p2  <<<dim3(BB*KD*NS*DIC/256), blk, 0, stream>>>(cumdt, hp, alog_i, gnstats);
    k_p3  <<<dim3(BB*2*NCH*DIC/256), blk, 0, stream>>>(xi_t, xdbl, dtp_w_i, dtp_b_i, alog_i, Ds_i, hp, y_t);
    k_lnz <<<dim3(BB*LL/4), blk, 0, stream>>>(y_t, z_t, ong_i, onb_i, x);
    k_oproj<<<dim3(BB*64*2), dim3(512), 0, stream>>>(y_t, op_w_i, x);
    k_gnA <<<dim3(BB*GRP*16), blk, 0, stream>>>(x, gnstats);
    k_dense1<<<dim3(BB*18*16), blk, 0, stream>>>(x, gnstats, gn_g_i, gn_b_i, l1_w_i, l1_b_i, tmp);
    k_dense2<<<dim3(BB*18*16), blk, 0, stream>>>(tmp, l2_w_i, l2_b_i, x,
                                                 (i==NLAYER-1) ? tmp_pad : (float*)nullptr);
  }

  hipMemsetAsync(tmp, 0, (size_t)BB*CI*LL*sizeof(float), stream);
  k_shrinkA<<<dim3(BB*24*16), blk, 0, stream>>>(tmp_pad, sh_w, tmp);
  k_sig<<<dim3((BB*CI*LL+255)/256), blk, 0, stream>>>(tmp, sh_b, (float*)d_out);
}

// Round 15
// 529.913 us; speedup vs baseline: 1.1301x; 1.1301x over previous
//
#include <hip/hip_runtime.h>
#include <math.h>

#define BB 4
#define CI 6
#define LL 4096
#define DMC 72
#define DIC 144
#define KD 4
#define NS 8
#define RD 4
#define NLAYER 2
#define GRP 12
#define NCH 256   // chunks per scan
#define TS 16     // steps per chunk
#define SP 72     // padded row stride (left pad 4 -> 4-elem aligned interior)
#define PPN (66*SP)
#define L2E 1.4426950408889634f

__device__ __forceinline__ float sigmoidf_(float x){ return 1.f/(1.f+__expf(-x)); }
__device__ __forceinline__ float siluf_(float x){ return x*sigmoidf_(x); }
__device__ __forceinline__ float softplusf_(float x){
  return fmaxf(x,0.f) + __logf(1.f + __expf(-fabsf(x)));
}

__device__ __forceinline__ int padidx(int p){ return SP*(p>>6) + (p&63) + SP + 4; }

#define LOAD9(ip, a) do { \
  a[0]=(ip)[-SP-1]; a[1]=(ip)[-SP]; a[2]=(ip)[-SP+1]; \
  a[3]=(ip)[-1];    a[4]=(ip)[0];   a[5]=(ip)[1];     \
  a[6]=(ip)[SP-1];  a[7]=(ip)[SP];  a[8]=(ip)[SP+1];  } while(0)

// 6 contiguous values (cols -1..4), base 4-elem aligned
__device__ __forceinline__ void load6(const float* __restrict__ base, float v[6]){
  v[0] = base[-1];
  float4 f = *(const float4*)base;
  v[1]=f.x; v[2]=f.y; v[3]=f.z; v[4]=f.w;
  v[5] = base[4];
}

// ---------- zero halos of all padded planes ----------
__global__ void k_halo(float* __restrict__ pads, int nplanes){
  int plane = blockIdx.x;
  if (plane >= nplanes) return;
  int t = threadIdx.x;
  if (t >= 260) return;
  float* pl = pads + (size_t)plane*PPN;
  int row, col;
  if (t < 132){
    row = (t < 66) ? 0 : 65;
    col = 3 + (t % 66);
  } else {
    int j = t - 132;
    col = (j < 64) ? 3 : 68;
    row = 1 + (j & 63);
  }
  pl[row*SP + col] = 0.f;
}

// ---------- pad copy of the input image ----------
__global__ void k_pad_img(const float* __restrict__ img, float* __restrict__ img_pad){
  int idx = blockIdx.x*256 + threadIdx.x;
  if (idx >= BB*CI*LL) return;
  int p = idx & 4095; int bc = idx >> 12;
  img_pad[(size_t)bc*PPN + padidx(p)] = img[idx];
}

// ---------- conv 6->72 3x3 + lrelu(0.01); 4 px/thread ----------
__global__ void k_conv1(const float* __restrict__ img_pad, const float* __restrict__ w,
                        const float* __restrict__ bias, float* __restrict__ tmp_pad){
  int bid = blockIdx.x;
  int tile = bid & 3; int r = bid >> 2; int o = r % DMC; int b = r / DMC;
  int p0 = tile*1024 + threadIdx.x*4;
  int pb = padidx(p0);
  float bv = bias[o];
  float acc[4] = {bv,bv,bv,bv};
  #pragma unroll
  for (int ic=0; ic<CI; ++ic){
    const float* ip = img_pad + (size_t)(b*CI+ic)*PPN + pb;
    const float* wr = w + (o*CI+ic)*9;
    #pragma unroll
    for (int rr=0; rr<3; ++rr){
      float v[6]; load6(ip + (rr-1)*SP, v);
      float w0=wr[rr*3], w1=wr[rr*3+1], w2v=wr[rr*3+2];
      #pragma unroll
      for (int q=0;q<4;++q) acc[q] += v[q]*w0 + v[q+1]*w1 + v[q+2]*w2v;
    }
  }
  #pragma unroll
  for (int q=0;q<4;++q) acc[q] = acc[q] >= 0.f ? acc[q] : 0.01f*acc[q];
  *(float4*)(tmp_pad + (size_t)(b*DMC+o)*PPN + pb) = make_float4(acc[0],acc[1],acc[2],acc[3]);
}

// ---------- conv2 init: bias + 1x1 shortcut -> x ----------
__global__ void k_conv2init(const float* __restrict__ img, const float* __restrict__ b2,
                            const float* __restrict__ wsc, const float* __restrict__ bsc,
                            float* __restrict__ xout){
  int bid = blockIdx.x;
  int t = bid & 15; int r = bid >> 4; int og = r % 18; int b = r / 18;
  int p = t*256 + threadIdx.x;
  float acc[4];
  #pragma unroll
  for (int j=0;j<4;++j) acc[j] = b2[og*4+j] + bsc[og*4+j];
  #pragma unroll
  for (int ic=0; ic<CI; ++ic){
    float v = img[((b*CI+ic)<<12)+p];
    #pragma unroll
    for (int j=0;j<4;++j) acc[j] += v * wsc[(og*4+j)*CI+ic];
  }
  #pragma unroll
  for (int j=0;j<4;++j)
    xout[((b*DMC+og*4+j)<<12)+p] = acc[j];
}

// ---------- conv2: 3x3 partials; 1 px x 4 oc /thread; ic-split x2; coalesced atomics ----------
__global__ void k_conv2(const float* __restrict__ tmp_pad,
                        const float* __restrict__ w2, float* __restrict__ xout){
  int bid = blockIdx.x;
  int t = bid & 15; int r = bid >> 4; int og = r % 18; r /= 18;
  int icg = r & 1; int b = r >> 1;
  int p = t*256 + threadIdx.x;
  int pb = padidx(p);
  float acc[4] = {0.f,0.f,0.f,0.f};
  const float* ipb = tmp_pad + (size_t)b*DMC*PPN + pb;
  const float* wb  = w2 + (size_t)(og*4)*DMC*9;
  #pragma unroll 2
  for (int ii=0; ii<36; ++ii){
    int ic = icg*36 + ii;
    const float* ip = ipb + (size_t)ic*PPN;
    float a[9]; LOAD9(ip, a);
    const float* wp = wb + ic*9;
    #pragma unroll
    for (int j=0;j<4;++j){
      float s = 0.f;
      #pragma unroll
      for (int q=0;q<9;++q) s += a[q]*wp[(size_t)j*DMC*9 + q];
      acc[j] += s;
    }
  }
  #pragma unroll
  for (int j=0;j<4;++j)
    atomicAdd(xout + ((b*DMC+og*4+j)<<12)+p, acc[j]);
}

// ---------- xz: 144 ch -> padded planes; z -> z_t [b][p][c] ----------
__global__ void k_xz(const float* __restrict__ x, const float* __restrict__ inw,
                     float* __restrict__ xz_pad, float* __restrict__ z_t, int relu){
  int bid = blockIdx.x;
  int t = bid & 15; int r = bid >> 4; int eg = r % 36; int b = r / 36;
  int p = t*256 + threadIdx.x;
  float acc[8] = {0.f,0.f,0.f,0.f,0.f,0.f,0.f,0.f};
  for (int c0=0; c0<DMC; c0+=4){
    float a[4];
    #pragma unroll
    for (int q=0;q<4;++q) a[q] = x[((b*DMC+c0+q)<<12)+p];
    if (relu){
      #pragma unroll
      for (int q=0;q<4;++q) a[q] = a[q] >= 0.f ? a[q] : 0.01f*a[q];
    }
    #pragma unroll
    for (int j=0;j<8;++j){
      float4 w = *(const float4*)(inw + (eg*8+j)*DMC + c0);
      acc[j] += a[0]*w.x + a[1]*w.y + a[2]*w.z + a[3]*w.w;
    }
  }
  if (eg < 18){
    int pb = padidx(p);
    #pragma unroll
    for (int j=0;j<8;++j) xz_pad[(size_t)(b*DIC+eg*8+j)*PPN + pb] = acc[j];
  } else {
    float* zb = z_t + ((size_t)b*LL+p)*DIC + (eg*8-DIC);
    *(float4*)(zb)   = make_float4(acc[0],acc[1],acc[2],acc[3]);
    *(float4*)(zb+4) = make_float4(acc[4],acc[5],acc[6],acc[7]);
  }
}

// ---------- depthwise 3x3 + bias + silu; 4 px/thread -> xi_t [b][p][c] ----------
__global__ void k_dw(const float* __restrict__ xz_pad, const float* __restrict__ dww,
                     const float* __restrict__ dwb, float* __restrict__ xi_t){
  int bid = blockIdx.x;
  int tile = bid & 3; int r = bid >> 2; int c = r % DIC; int b = r / DIC;
  int p0 = tile*1024 + threadIdx.x*4;
  int pb = padidx(p0);
  const float* ip = xz_pad + (size_t)(b*DIC+c)*PPN + pb;
  const float* wp = dww + c*9;
  float bv = dwb[c];
  float acc[4] = {bv,bv,bv,bv};
  #pragma unroll
  for (int rr=0; rr<3; ++rr){
    float v[6]; load6(ip + (rr-1)*SP, v);
    float w0=wp[rr*3], w1=wp[rr*3+1], w2v=wp[rr*3+2];
    #pragma unroll
    for (int q=0;q<4;++q) acc[q] += v[q]*w0 + v[q+1]*w1 + v[q+2]*w2v;
  }
  #pragma unroll
  for (int q=0;q<4;++q)
    xi_t[((size_t)b*LL+p0+q)*DIC + c] = siluf_(acc[q]);
}

// ---------- x_dbl [bk][p][20]; 4 parts of 5 ch ----------
__global__ void k_xdbl(const float* __restrict__ xi_t, const float* __restrict__ xpw,
                       float* __restrict__ xdbl){
  int bid = blockIdx.x;
  int t = bid & 15; int r = bid >> 4;
  int kk = r & 3; r >>= 2; int part = r & 3; int b = r >> 2;
  int p = t*256 + threadIdx.x;
  const float* xib = xi_t + ((size_t)b*LL + p)*DIC;
  const float* wk = xpw + (size_t)(kk*20 + part*5)*DIC;
  float acc[5] = {0.f,0.f,0.f,0.f,0.f};
  for (int d=0; d<DIC; d+=4){
    float4 v = *(const float4*)(xib + d);
    #pragma unroll
    for (int c=0;c<5;++c){
      float4 w = *(const float4*)(wk + (size_t)c*DIC + d);
      acc[c] += v.x*w.x + v.y*w.y + v.z*w.z + v.w*w.w;
    }
  }
  float* dst = xdbl + ((size_t)(b*KD+kk)*LL + p)*20 + part*5;
  #pragma unroll
  for (int c=0;c<5;++c) dst[c] = acc[c];
}

__device__ __forceinline__ void scan_decode(int idx, int& b, int& k, int& ch, int& c){
  c = idx % DIC;
  int r = idx / DIC;
  ch = r % NCH;
  r /= NCH;
  k = r & 3; b = r >> 2;
}

// affine scan-position: ps(t) = ps0 + t*sk within a chunk (no 64-boundary carry: TS=16)
__device__ __forceinline__ void scan_affine(int k, int ch, int& ps0, int& sk){
  int l0 = ch*TS;
  if (k == 0){ ps0 = l0; sk = 1; }
  else if (k == 1){ ps0 = ((l0 & 63) << 6) | (l0 >> 6); sk = 64; }
  else if (k == 2){ ps0 = (LL-1) - l0; sk = -1; }
  else { int m0 = (LL-1) - l0; ps0 = ((m0 & 63) << 6) | (m0 >> 6); sk = -64; }
}

// ---------- P1: local scans; stores hp + cumdt (scalar); zeroes y_t (4 strided stores) ----------
__global__ void k_p1(const float* __restrict__ xi_t, const float* __restrict__ xdbl,
                     const float* __restrict__ dtpw, const float* __restrict__ dtpb,
                     const float* __restrict__ alog,
                     float* __restrict__ cumdt, float* __restrict__ hp,
                     float* __restrict__ y_t){
  int idx = blockIdx.x*256 + threadIdx.x;
  if (idx >= BB*KD*NCH*DIC) return;
  // zero y_t: 4 coalesced strided stores cover BB*LL*DIC = 4 * BB*KD*NCH*DIC
  const int NQ = BB*KD*NCH*DIC;
  #pragma unroll
  for (int j=0;j<4;++j) y_t[idx + (size_t)j*NQ] = 0.f;
  int b,k,ch,c; scan_decode(idx,b,k,ch,c);
  float Arow[NS];
  #pragma unroll
  for (int n=0;n<NS;++n) Arow[n] = -__expf(alog[(k*DIC+c)*NS+n]) * L2E;
  float4 wdt = *(const float4*)(dtpw + (k*DIC+c)*RD);
  float bdt = dtpb[k*DIC+c];
  int ps0, sk; scan_affine(k, ch, ps0, sk);
  const float* row = xdbl + (size_t)(b*KD+k)*LL*20 + (size_t)ps0*20;
  const float* up  = xi_t + (size_t)b*LL*DIC + c + (size_t)ps0*DIC;
  long rstep = (long)sk*20;
  long ustep = (long)sk*DIC;
  float h[NS];
  #pragma unroll
  for (int n=0;n<NS;++n) h[n]=0.f;
  float sumd = 0.f;
  #pragma unroll 4
  for (int t=0; t<TS; ++t){
    float4 q0 = *(const float4*)(row);
    float4 q1 = *(const float4*)(row+4);
    float4 q2 = *(const float4*)(row+8);
    float u = *up;
    float dt = bdt + q0.x*wdt.x + q0.y*wdt.y + q0.z*wdt.z + q0.w*wdt.w;
    dt = softplusf_(dt);
    sumd += dt;
    float du = dt*u;
    float Bv[NS] = {q1.x,q1.y,q1.z,q1.w,q2.x,q2.y,q2.z,q2.w};
    #pragma unroll
    for (int n=0;n<NS;++n)
      h[n] = h[n]*exp2f(dt*Arow[n]) + du*Bv[n];
    row += rstep; up += ustep;
  }
  size_t base = ((size_t)((b*KD+k)*NCH + ch)*NS)*DIC + c;
  #pragma unroll
  for (int n=0;n<NS;++n) hp[base + n*DIC] = h[n];
  cumdt[((size_t)((b*KD+k)*NCH + ch))*DIC + c] = sumd;
}

// ---------- P2: prefix via cumdt; zeroes gnstats ----------
__global__ void k_p2(const float* __restrict__ cumdt, float* __restrict__ hp,
                     const float* __restrict__ alog, float* __restrict__ gnstats){
  if (blockIdx.x == 0 && threadIdx.x < 2*BB*GRP) gnstats[threadIdx.x] = 0.f;
  int idx = blockIdx.x*256 + threadIdx.x;
  if (idx >= BB*KD*NS*DIC) return;
  int c = idx % DIC; int n = (idx/DIC) % NS; int bk = idx/(DIC*NS);
  int k = bk & 3;
  float Arow = -__expf(alog[(k*DIC+c)*NS+n]) * L2E;
  float h = 0.f;
  #pragma unroll 4
  for (int ch=0; ch<NCH; ++ch){
    float sd = cumdt[((size_t)(bk*NCH+ch))*DIC + c];
    float a = exp2f(sd*Arow);
    size_t base = ((size_t)(bk*NCH+ch)*NS + n)*DIC + c;
    float pp = hp[base];
    hp[base] = h;
    h = a*h + pp;
  }
}

// ---------- P3: replay chunks (one direction/thread), atomic accumulate into y_t ----------
__global__ void k_p3(const float* __restrict__ xi_t, const float* __restrict__ xdbl,
                     const float* __restrict__ dtpw, const float* __restrict__ dtpb,
                     const float* __restrict__ alog, const float* __restrict__ Dsv,
                     const float* __restrict__ hin, float* __restrict__ y_t){
  int idx = blockIdx.x*256 + threadIdx.x;
  if (idx >= BB*KD*NCH*DIC) return;
  int b,k,ch,c; scan_decode(idx,b,k,ch,c);
  float Arow[NS];
  #pragma unroll
  for (int n=0;n<NS;++n) Arow[n] = -__expf(alog[(k*DIC+c)*NS+n]) * L2E;
  float4 wdt = *(const float4*)(dtpw + (k*DIC+c)*RD);
  float bdt = dtpb[k*DIC+c];
  float Dv = Dsv[k*DIC+c];
  int ps0, sk; scan_affine(k, ch, ps0, sk);
  const float* row = xdbl + (size_t)(b*KD+k)*LL*20 + (size_t)ps0*20;
  const float* up  = xi_t + (size_t)b*LL*DIC + c + (size_t)ps0*DIC;
  float* yp        = y_t  + (size_t)b*LL*DIC + c + (size_t)ps0*DIC;
  long rstep = (long)sk*20;
  long ustep = (long)sk*DIC;
  float h[NS];
  size_t base = ((size_t)((b*KD+k)*NCH + ch)*NS)*DIC + c;
  #pragma unroll
  for (int n=0;n<NS;++n) h[n] = hin[base + n*DIC];
  #pragma unroll 4
  for (int t=0; t<TS; ++t){
    float4 q0 = *(const float4*)(row);
    float4 q1 = *(const float4*)(row+4);
    float4 q2 = *(const float4*)(row+8);
    float4 q3 = *(const float4*)(row+12);
    float4 q4 = *(const float4*)(row+16);
    float u = *up;
    float dt = bdt + q0.x*wdt.x + q0.y*wdt.y + q0.z*wdt.z + q0.w*wdt.w;
    dt = softplusf_(dt);
    float du = dt*u;
    float Bv[NS] = {q1.x,q1.y,q1.z,q1.w,q2.x,q2.y,q2.z,q2.w};
    float Cv[NS] = {q3.x,q3.y,q3.z,q3.w,q4.x,q4.y,q4.z,q4.w};
    float y = 0.f;
    #pragma unroll
    for (int n=0;n<NS;++n){
      h[n] = h[n]*exp2f(dt*Arow[n]) + du*Bv[n];
      y += h[n]*Cv[n];
    }
    y += u*Dv;
    atomicAdd(yp, y);
    row += rstep; up += ustep; yp += ustep;
  }
}

// ---------- LN over c per pixel (wave-per-pixel), *ong+onb, *silu(z); also zeroes x ----------
__global__ void k_lnz(float* __restrict__ y_t, const float* __restrict__ z_t,
                      const float* __restrict__ ong, const float* __restrict__ onb,
                      float* __restrict__ xzero){
  int gid = blockIdx.x*256 + threadIdx.x;
  // zero x (dead between xz and oproj) for oproj's atomic partials
  xzero[gid] = 0.f;
  if (gid < (int)(BB*DMC*LL - BB*LL*64)) xzero[gid + BB*LL*64] = 0.f;
  int wid = gid >> 6;
  int lane = gid & 63;
  if (wid >= BB*LL) return;
  size_t rb = (size_t)wid * DIC;
  float v0 = y_t[rb + lane];
  float v1 = y_t[rb + 64 + lane];
  float v2 = (lane < 16) ? y_t[rb + 128 + lane] : 0.f;
  float s = v0 + v1 + v2;
  float q = v0*v0 + v1*v1 + v2*v2;
  #pragma unroll
  for (int o=32; o>0; o>>=1){ s += __shfl_xor(s,o,64); q += __shfl_xor(q,o,64); }
  float mu = s*(1.f/DIC);
  float var = q*(1.f/DIC) - mu*mu;
  float rs = rsqrtf(var + 1e-5f);
  float z0 = z_t[rb + lane];
  y_t[rb + lane] = ((v0-mu)*rs*ong[lane] + onb[lane]) * siluf_(z0);
  float z1 = z_t[rb + 64 + lane];
  y_t[rb + 64 + lane] = ((v1-mu)*rs*ong[64+lane] + onb[64+lane]) * siluf_(z1);
  if (lane < 16){
    float z2 = z_t[rb + 128 + lane];
    y_t[rb + 128 + lane] = ((v2-mu)*rs*ong[128+lane] + onb[128+lane]) * siluf_(z2);
  }
}

// ---------- out-proj matmul, LDS-staged, d-split x2, atomic partials into x ----------
__global__ void k_oproj(const float* __restrict__ yn, const float* __restrict__ opw,
                        float* __restrict__ xout){
  __shared__ float ly[72*65];
  int bid = blockIdx.x;            // BB * 64 tiles * 2 dhalves
  int dhalf = bid & 1; int r = bid >> 1;
  int tile = r & 63; int b = r >> 6;
  int pstart = tile*64;
  const float* src = yn + ((size_t)b*LL + pstart)*DIC + dhalf*72;
  for (int i = threadIdx.x; i < 64*72; i += 512){
    int px = i / 72; int d = i - px*72;
    ly[d*65 + px] = src[(size_t)px*DIC + d];
  }
  __syncthreads();
  int px = threadIdx.x & 63;
  int ocg = __builtin_amdgcn_readfirstlane(threadIdx.x >> 6);  // 0..7 wave-uniform
  float acc[9];
  #pragma unroll
  for (int j=0;j<9;++j) acc[j]=0.f;
  const float* wb = opw + (size_t)ocg*9*DIC + dhalf*72;
  #pragma unroll 4
  for (int d=0; d<72; ++d){
    float a = ly[d*65 + px];
    #pragma unroll
    for (int j=0;j<9;++j) acc[j] += a * wb[(size_t)j*DIC + d];
  }
  #pragma unroll
  for (int j=0;j<9;++j)
    atomicAdd(xout + ((size_t)(b*DMC + ocg*9 + j)<<12) + pstart + px, acc[j]);
}

// ---------- groupnorm stats: partial sums -> atomic (sum, sumsq) per (b,group) ----------
__global__ void k_gnA(const float* __restrict__ x, float* __restrict__ stats){
  __shared__ float s1[256], s2[256];
  int bid = blockIdx.x;    // BB*GRP*16
  int t = bid & 15; int r = bid >> 4; int gr = r % GRP; int b = r / GRP;
  float ls=0.f, lq=0.f;
  #pragma unroll
  for (int it=0; it<6; ++it){
    int i = t*1536 + it*256 + threadIdx.x;   // i in [0, 24576)
    int c = gr*6 + (i>>12); int p = i & 4095;
    float v = x[((size_t)(b*DMC+c)<<12)+p];
    ls += v; lq += v*v;
  }
  s1[threadIdx.x]=ls; s2[threadIdx.x]=lq; __syncthreads();
  for (int s=128; s>0; s>>=1){
    if (threadIdx.x < s){ s1[threadIdx.x]+=s1[threadIdx.x+s]; s2[threadIdx.x]+=s2[threadIdx.x+s]; }
    __syncthreads();
  }
  if (threadIdx.x == 0){
    atomicAdd(stats + (b*GRP+gr)*2,     s1[0]);
    atomicAdd(stats + (b*GRP+gr)*2 + 1, s2[0]);
  }
}

// ---------- dense1: l1( gn(x) ), GN A/B computed in-block ----------
__global__ void k_dense1(const float* __restrict__ xin, const float* __restrict__ gnstats,
                         const float* __restrict__ gng, const float* __restrict__ gnb,
                         const float* __restrict__ w, const float* __restrict__ bias,
                         float* __restrict__ xout){
  __shared__ float As[DMC], Bs[DMC];
  int bid = blockIdx.x;
  int t = bid & 15; int r = bid >> 4; int eg = r % 18; int b = r / 18;
  if (threadIdx.x < DMC){
    int c = threadIdx.x; int gr = c/6;
    float s = gnstats[(b*GRP+gr)*2];
    float q = gnstats[(b*GRP+gr)*2 + 1];
    const float inv = 1.f/(6.f*LL);
    float mu = s*inv;
    float var = q*inv - mu*mu;
    float rs = rsqrtf(var + 1e-5f);
    float A = rs*gng[c];
    As[c] = A;
    Bs[c] = gnb[c] - mu*A;
  }
  __syncthreads();
  int p = t*256 + threadIdx.x;
  float acc[4];
  #pragma unroll
  for (int j=0;j<4;++j) acc[j] = bias[eg*4+j];
  for (int c0=0; c0<DMC; c0+=4){
    float a[4];
    #pragma unroll
    for (int q=0;q<4;++q){
      float v = xin[((size_t)(b*DMC+c0+q)<<12)+p];
      a[q] = v*As[c0+q] + Bs[c0+q];
    }
    #pragma unroll
    for (int j=0;j<4;++j){
      float4 w0 = *(const float4*)(w + (eg*4+j)*DMC + c0);
      acc[j] += a[0]*w0.x + a[1]*w0.y + a[2]*w0.z + a[3]*w0.w;
    }
  }
  #pragma unroll
  for (int j=0;j<4;++j)
    xout[((size_t)(b*DMC+eg*4+j)<<12)+p] = acc[j];
}

// ---------- dense2: l2( lrelu(tmp) ) ----------
__global__ void k_dense2(const float* __restrict__ xin, const float* __restrict__ w,
                         const float* __restrict__ bias, float* __restrict__ xout,
                         float* __restrict__ pad_out){
  int bid = blockIdx.x;
  int t = bid & 15; int r = bid >> 4; int eg = r % 18; int b = r / 18;
  int p = t*256 + threadIdx.x;
  float acc[4];
  #pragma unroll
  for (int j=0;j<4;++j) acc[j] = bias[eg*4+j];
  for (int c0=0; c0<DMC; c0+=4){
    float a[4];
    #pragma unroll
    for (int q=0;q<4;++q){
      float v = xin[((size_t)(b*DMC+c0+q)<<12)+p];
      a[q] = v >= 0.f ? v : 0.04f*v;
    }
    #pragma unroll
    for (int j=0;j<4;++j){
      float4 w0 = *(const float4*)(w + (eg*4+j)*DMC + c0);
      acc[j] += a[0]*w0.x + a[1]*w0.y + a[2]*w0.z + a[3]*w0.w;
    }
  }
  int pb = padidx(p);
  #pragma unroll
  for (int j=0;j<4;++j){
    xout[((size_t)(b*DMC+eg*4+j)<<12)+p] = acc[j];
    if (pad_out) pad_out[(size_t)(b*DMC+eg*4+j)*PPN + pb] = acc[j];
  }
}

// ---------- shrink conv pass A ----------
__global__ void k_shrinkA(const float* __restrict__ x_pad, const float* __restrict__ w,
                          float* __restrict__ pacc){
  int bid = blockIdx.x;
  int t = bid & 15; int r = bid >> 4; int icg = r % 24; int b = r / 24;
  int p = t*256 + threadIdx.x;
  int pb = padidx(p);
  float acc[6] = {0.f,0.f,0.f,0.f,0.f,0.f};
  const float* ipb = x_pad + (size_t)b*DMC*PPN + pb;
  #pragma unroll
  for (int ii=0; ii<3; ++ii){
    int ic = icg*3 + ii;
    const float* ip = ipb + (size_t)ic*PPN;
    float a[9]; LOAD9(ip, a);
    #pragma unroll
    for (int o=0;o<6;++o){
      const float* wp = w + (o*DMC+ic)*9;
      float s = 0.f;
      #pragma unroll
      for (int q=0;q<9;++q) s += a[q]*wp[q];
      acc[o] += s;
    }
  }
  #pragma unroll
  for (int o=0;o<6;++o)
    atomicAdd(pacc + ((size_t)(b*CI+o)<<12)+p, acc[o]);
}

// ---------- shrink pass B ----------
__global__ void k_sig(const float* __restrict__ pacc, const float* __restrict__ bias,
                      float* __restrict__ out){
  int idx = blockIdx.x*256 + threadIdx.x;
  if (idx >= BB*CI*LL) return;
  int o = (idx>>12) % CI;
  out[idx] = sigmoidf_(pacc[idx] + bias[o]);
}

extern "C" void kernel_launch(void* const* d_in, const int* in_sizes, int n_in,
                              void* d_out, int out_size, void* d_ws, size_t ws_size,
                              hipStream_t stream){
  const float* image = (const float*)d_in[0];
  const float* cb_w1 = (const float*)d_in[1];
  const float* cb_b1 = (const float*)d_in[2];
  const float* cb_w2 = (const float*)d_in[3];
  const float* cb_b2 = (const float*)d_in[4];
  const float* cb_ws = (const float*)d_in[5];
  const float* cb_bs = (const float*)d_in[6];
  const float* in_w  = (const float*)d_in[7];
  const float* dw_w  = (const float*)d_in[8];
  const float* dw_b  = (const float*)d_in[9];
  const float* xp_w  = (const float*)d_in[10];
  const float* dtp_w = (const float*)d_in[11];
  const float* dtp_b = (const float*)d_in[12];
  const float* A_logs= (const float*)d_in[13];
  const float* Ds    = (const float*)d_in[14];
  const float* ong   = (const float*)d_in[15];
  const float* onb   = (const float*)d_in[16];
  const float* op_w  = (const float*)d_in[17];
  const float* gn_g  = (const float*)d_in[18];
  const float* gn_b  = (const float*)d_in[19];
  const float* l1_w  = (const float*)d_in[20];
  const float* l1_b  = (const float*)d_in[21];
  const float* l2_w  = (const float*)d_in[22];
  const float* l2_b  = (const float*)d_in[23];
  const float* sh_w  = (const float*)d_in[24];
  const float* sh_b  = (const float*)d_in[25];

  const size_t SZ_X  = (size_t)BB*DMC*LL;
  const size_t SZ_C  = (size_t)BB*DIC*LL;
  const size_t SZ_XD = (size_t)BB*KD*20*LL;
  const size_t SZ_CD = (size_t)BB*KD*NCH*DIC;    // cumdt
  const size_t SZ_HP = (size_t)BB*KD*NCH*NS*DIC;
  const size_t SZ_IP = (size_t)BB*CI*PPN;
  const size_t SZ_TP = (size_t)BB*DMC*PPN;
  const size_t SZ_ZP = (size_t)BB*DIC*PPN;

  float* ws = (float*)d_ws;
  size_t off = 0;
  float* x     = ws + off; off += SZ_X;
  float* tmp   = ws + off; off += SZ_X;
  float* z_t   = ws + off; off += SZ_C;
  float* xi_t  = ws + off; off += SZ_C;
  float* xdbl  = ws + off; off += SZ_XD;
  float* y_t   = ws + off; off += SZ_C;
  float* cumdt = ws + off; off += SZ_CD;
  float* hp    = ws + off; off += SZ_HP;
  float* pads  = ws + off;
  float* img_pad = pads;
  float* tmp_pad = img_pad + SZ_IP;
  float* xz_pad  = tmp_pad + SZ_TP;
  off += SZ_IP + SZ_TP + SZ_ZP;
  float* gnstats = ws + off; off += 2*BB*GRP;
  if (ws_size < off*sizeof(float)) return;

  dim3 blk(256);
  const int NPLANES = BB*CI + BB*DMC + BB*DIC;

  k_halo<<<dim3(NPLANES), blk, 0, stream>>>(pads, NPLANES);
  k_pad_img<<<dim3(BB*CI*16), blk, 0, stream>>>(image, img_pad);
  k_conv1<<<dim3(BB*DMC*4), blk, 0, stream>>>(img_pad, cb_w1, cb_b1, tmp_pad);
  k_conv2init<<<dim3(BB*18*16), blk, 0, stream>>>(image, cb_b2, cb_ws, cb_bs, x);
  k_conv2<<<dim3(BB*2*18*16), blk, 0, stream>>>(tmp_pad, cb_w2, x);

  for (int i=0; i<NLAYER; ++i){
    const float* in_w_i  = in_w  + (size_t)i*2*DIC*DMC;
    const float* dw_w_i  = dw_w  + (size_t)i*DIC*9;
    const float* dw_b_i  = dw_b  + (size_t)i*DIC;
    const float* xp_w_i  = xp_w  + (size_t)i*KD*20*DIC;
    const float* dtp_w_i = dtp_w + (size_t)i*KD*DIC*RD;
    const float* dtp_b_i = dtp_b + (size_t)i*KD*DIC;
    const float* alog_i  = A_logs+ (size_t)i*KD*DIC*NS;
    const float* Ds_i    = Ds    + (size_t)i*KD*DIC;
    const float* ong_i   = ong   + (size_t)i*DIC;
    const float* onb_i   = onb   + (size_t)i*DIC;
    const float* op_w_i  = op_w  + (size_t)i*DMC*DIC;
    const float* gn_g_i  = gn_g  + (size_t)i*DMC;
    const float* gn_b_i  = gn_b  + (size_t)i*DMC;
    const float* l1_w_i  = l1_w  + (size_t)i*DMC*DMC;
    const float* l1_b_i  = l1_b  + (size_t)i*DMC;
    const float* l2_w_i  = l2_w  + (size_t)i*DMC*DMC;
    const float* l2_b_i  = l2_b  + (size_t)i*DMC;

    k_xz  <<<dim3(BB*36*16), blk, 0, stream>>>(x, in_w_i, xz_pad, z_t, (i==0)?1:0);
    k_dw  <<<dim3(BB*DIC*4), blk, 0, stream>>>(xz_pad, dw_w_i, dw_b_i, xi_t);
    k_xdbl<<<dim3(BB*4*KD*16), blk, 0, stream>>>(xi_t, xp_w_i, xdbl);
    k_p1  <<<dim3(BB*KD*NCH*DIC/256), blk, 0, stream>>>(xi_t, xdbl, dtp_w_i, dtp_b_i, alog_i, cumdt, hp, y_t);
    k_p2  <<<dim3(BB*KD*NS*DIC/256), blk, 0, stream>>>(cumdt, hp, alog_i, gnstats);
    k_p3  <<<dim3(BB*KD*NCH*DIC/256), blk, 0, stream>>>(xi_t, xdbl, dtp_w_i, dtp_b_i, alog_i, Ds_i, hp, y_t);
    k_lnz <<<dim3(BB*LL/4), blk, 0, stream>>>(y_t, z_t, ong_i, onb_i, x);
    k_oproj<<<dim3(BB*64*2), dim3(512), 0, stream>>>(y_t, op_w_i, x);
    k_gnA <<<dim3(BB*GRP*16), blk, 0, stream>>>(x, gnstats);
    k_dense1<<<dim3(BB*18*16), blk, 0, stream>>>(x, gnstats, gn_g_i, gn_b_i, l1_w_i, l1_b_i, tmp);
    k_dense2<<<dim3(BB*18*16), blk, 0, stream>>>(tmp, l2_w_i, l2_b_i, x,
                                                 (i==NLAYER-1) ? tmp_pad : (float*)nullptr);
  }

  hipMemsetAsync(tmp, 0, (size_t)BB*CI*LL*sizeof(float), stream);
  k_shrinkA<<<dim3(BB*24*16), blk, 0, stream>>>(tmp_pad, sh_w, tmp);
  k_sig<<<dim3((BB*CI*LL+255)/256), blk, 0, stream>>>(tmp, sh_b, (float*)d_out);
}

// Round 16
// 495.132 us; speedup vs baseline: 1.2095x; 1.0702x over previous
//
#include <hip/hip_runtime.h>
#include <math.h>

#define BB 4
#define CI 6
#define LL 4096
#define DMC 72
#define DIC 144
#define KD 4
#define NS 8
#define RD 4
#define NLAYER 2
#define GRP 12
#define NCH 256   // chunks per scan
#define TS 16     // steps per chunk
#define SP 72     // padded row stride (left pad 4 -> 4-elem aligned interior)
#define PPN (66*SP)
#define L2E 1.4426950408889634f

__device__ __forceinline__ float sigmoidf_(float x){ return 1.f/(1.f+__expf(-x)); }
__device__ __forceinline__ float siluf_(float x){ return x*sigmoidf_(x); }
__device__ __forceinline__ float softplusf_(float x){
  return fmaxf(x,0.f) + __logf(1.f + __expf(-fabsf(x)));
}

__device__ __forceinline__ int padidx(int p){ return SP*(p>>6) + (p&63) + SP + 4; }

#define LOAD9(ip, a) do { \
  a[0]=(ip)[-SP-1]; a[1]=(ip)[-SP]; a[2]=(ip)[-SP+1]; \
  a[3]=(ip)[-1];    a[4]=(ip)[0];   a[5]=(ip)[1];     \
  a[6]=(ip)[SP-1];  a[7]=(ip)[SP];  a[8]=(ip)[SP+1];  } while(0)

// 6 contiguous values (cols -1..4), base 4-elem aligned
__device__ __forceinline__ void load6(const float* __restrict__ base, float v[6]){
  v[0] = base[-1];
  float4 f = *(const float4*)base;
  v[1]=f.x; v[2]=f.y; v[3]=f.z; v[4]=f.w;
  v[5] = base[4];
}

// ---------- prep: zero halos of all padded planes (260 cells, looped) + pad-copy image ----------
__global__ void k_prep(const float* __restrict__ img, float* __restrict__ pads,
                       float* __restrict__ img_pad, int nplanes){
  int bid = blockIdx.x;
  if (bid < nplanes){
    float* pl = pads + (size_t)bid*PPN;
    for (int t = threadIdx.x; t < 260; t += 256){
      int row, col;
      if (t < 132){
        row = (t < 66) ? 0 : 65;
        col = 3 + (t % 66);
      } else {
        int j = t - 132;
        col = (j < 64) ? 3 : 68;
        row = 1 + (j & 63);
      }
      pl[row*SP + col] = 0.f;
    }
  } else {
    int idx = (bid - nplanes)*256 + threadIdx.x;
    int p = idx & 4095; int bc = idx >> 12;
    img_pad[(size_t)bc*PPN + padidx(p)] = img[idx];
  }
}

// ---------- conv 6->72 3x3 + lrelu(0.01); 4 px/thread ----------
__global__ void k_conv1(const float* __restrict__ img_pad, const float* __restrict__ w,
                        const float* __restrict__ bias, float* __restrict__ tmp_pad){
  int bid = blockIdx.x;
  int tile = bid & 3; int r = bid >> 2; int o = r % DMC; int b = r / DMC;
  int p0 = tile*1024 + threadIdx.x*4;
  int pb = padidx(p0);
  float bv = bias[o];
  float acc[4] = {bv,bv,bv,bv};
  #pragma unroll
  for (int ic=0; ic<CI; ++ic){
    const float* ip = img_pad + (size_t)(b*CI+ic)*PPN + pb;
    const float* wr = w + (o*CI+ic)*9;
    #pragma unroll
    for (int rr=0; rr<3; ++rr){
      float v[6]; load6(ip + (rr-1)*SP, v);
      float w0=wr[rr*3], w1=wr[rr*3+1], w2v=wr[rr*3+2];
      #pragma unroll
      for (int q=0;q<4;++q) acc[q] += v[q]*w0 + v[q+1]*w1 + v[q+2]*w2v;
    }
  }
  #pragma unroll
  for (int q=0;q<4;++q) acc[q] = acc[q] >= 0.f ? acc[q] : 0.01f*acc[q];
  *(float4*)(tmp_pad + (size_t)(b*DMC+o)*PPN + pb) = make_float4(acc[0],acc[1],acc[2],acc[3]);
}

// ---------- conv2 init: bias + 1x1 shortcut -> x ----------
__global__ void k_conv2init(const float* __restrict__ img, const float* __restrict__ b2,
                            const float* __restrict__ wsc, const float* __restrict__ bsc,
                            float* __restrict__ xout){
  int bid = blockIdx.x;
  int t = bid & 15; int r = bid >> 4; int og = r % 18; int b = r / 18;
  int p = t*256 + threadIdx.x;
  float acc[4];
  #pragma unroll
  for (int j=0;j<4;++j) acc[j] = b2[og*4+j] + bsc[og*4+j];
  #pragma unroll
  for (int ic=0; ic<CI; ++ic){
    float v = img[((b*CI+ic)<<12)+p];
    #pragma unroll
    for (int j=0;j<4;++j) acc[j] += v * wsc[(og*4+j)*CI+ic];
  }
  #pragma unroll
  for (int j=0;j<4;++j)
    xout[((b*DMC+og*4+j)<<12)+p] = acc[j];
}

// ---------- conv2: 3x3 partials; 1 px x 4 oc /thread; ic-split x2; coalesced atomics ----------
__global__ void k_conv2(const float* __restrict__ tmp_pad,
                        const float* __restrict__ w2, float* __restrict__ xout){
  int bid = blockIdx.x;
  int t = bid & 15; int r = bid >> 4; int og = r % 18; r /= 18;
  int icg = r & 1; int b = r >> 1;
  int p = t*256 + threadIdx.x;
  int pb = padidx(p);
  float acc[4] = {0.f,0.f,0.f,0.f};
  const float* ipb = tmp_pad + (size_t)b*DMC*PPN + pb;
  const float* wb  = w2 + (size_t)(og*4)*DMC*9;
  #pragma unroll 2
  for (int ii=0; ii<36; ++ii){
    int ic = icg*36 + ii;
    const float* ip = ipb + (size_t)ic*PPN;
    float a[9]; LOAD9(ip, a);
    const float* wp = wb + ic*9;
    #pragma unroll
    for (int j=0;j<4;++j){
      float s = 0.f;
      #pragma unroll
      for (int q=0;q<9;++q) s += a[q]*wp[(size_t)j*DMC*9 + q];
      acc[j] += s;
    }
  }
  #pragma unroll
  for (int j=0;j<4;++j)
    atomicAdd(xout + ((b*DMC+og*4+j)<<12)+p, acc[j]);
}

// ---------- xz: 144 ch -> padded planes; z -> z_t [b][p][c] ----------
__global__ void k_xz(const float* __restrict__ x, const float* __restrict__ inw,
                     float* __restrict__ xz_pad, float* __restrict__ z_t, int relu){
  int bid = blockIdx.x;
  int t = bid & 15; int r = bid >> 4; int eg = r % 36; int b = r / 36;
  int p = t*256 + threadIdx.x;
  float acc[8] = {0.f,0.f,0.f,0.f,0.f,0.f,0.f,0.f};
  for (int c0=0; c0<DMC; c0+=4){
    float a[4];
    #pragma unroll
    for (int q=0;q<4;++q) a[q] = x[((b*DMC+c0+q)<<12)+p];
    if (relu){
      #pragma unroll
      for (int q=0;q<4;++q) a[q] = a[q] >= 0.f ? a[q] : 0.01f*a[q];
    }
    #pragma unroll
    for (int j=0;j<8;++j){
      float4 w = *(const float4*)(inw + (eg*8+j)*DMC + c0);
      acc[j] += a[0]*w.x + a[1]*w.y + a[2]*w.z + a[3]*w.w;
    }
  }
  if (eg < 18){
    int pb = padidx(p);
    #pragma unroll
    for (int j=0;j<8;++j) xz_pad[(size_t)(b*DIC+eg*8+j)*PPN + pb] = acc[j];
  } else {
    float* zb = z_t + ((size_t)b*LL+p)*DIC + (eg*8-DIC);
    *(float4*)(zb)   = make_float4(acc[0],acc[1],acc[2],acc[3]);
    *(float4*)(zb+4) = make_float4(acc[4],acc[5],acc[6],acc[7]);
  }
}

// ---------- depthwise 3x3 + bias + silu; 4 px/thread -> xi_t [b][p][c] ----------
__global__ void k_dw(const float* __restrict__ xz_pad, const float* __restrict__ dww,
                     const float* __restrict__ dwb, float* __restrict__ xi_t){
  int bid = blockIdx.x;
  int tile = bid & 3; int r = bid >> 2; int c = r % DIC; int b = r / DIC;
  int p0 = tile*1024 + threadIdx.x*4;
  int pb = padidx(p0);
  const float* ip = xz_pad + (size_t)(b*DIC+c)*PPN + pb;
  const float* wp = dww + c*9;
  float bv = dwb[c];
  float acc[4] = {bv,bv,bv,bv};
  #pragma unroll
  for (int rr=0; rr<3; ++rr){
    float v[6]; load6(ip + (rr-1)*SP, v);
    float w0=wp[rr*3], w1=wp[rr*3+1], w2v=wp[rr*3+2];
    #pragma unroll
    for (int q=0;q<4;++q) acc[q] += v[q]*w0 + v[q+1]*w1 + v[q+2]*w2v;
  }
  #pragma unroll
  for (int q=0;q<4;++q)
    xi_t[((size_t)b*LL+p0+q)*DIC + c] = siluf_(acc[q]);
}

// ---------- x_dbl [bk][p][20]; 4 parts of 5 ch ----------
__global__ void k_xdbl(const float* __restrict__ xi_t, const float* __restrict__ xpw,
                       float* __restrict__ xdbl){
  int bid = blockIdx.x;
  int t = bid & 15; int r = bid >> 4;
  int kk = r & 3; r >>= 2; int part = r & 3; int b = r >> 2;
  int p = t*256 + threadIdx.x;
  const float* xib = xi_t + ((size_t)b*LL + p)*DIC;
  const float* wk = xpw + (size_t)(kk*20 + part*5)*DIC;
  float acc[5] = {0.f,0.f,0.f,0.f,0.f};
  for (int d=0; d<DIC; d+=4){
    float4 v = *(const float4*)(xib + d);
    #pragma unroll
    for (int c=0;c<5;++c){
      float4 w = *(const float4*)(wk + (size_t)c*DIC + d);
      acc[c] += v.x*w.x + v.y*w.y + v.z*w.z + v.w*w.w;
    }
  }
  float* dst = xdbl + ((size_t)(b*KD+kk)*LL + p)*20 + part*5;
  #pragma unroll
  for (int c=0;c<5;++c) dst[c] = acc[c];
}

__device__ __forceinline__ void scan_decode(int idx, int& b, int& k, int& ch, int& c){
  c = idx % DIC;
  int r = idx / DIC;
  ch = r % NCH;
  r /= NCH;
  k = r & 3; b = r >> 2;
}

// affine scan-position: ps(t) = ps0 + t*sk within a chunk (no 64-boundary carry: TS=16)
__device__ __forceinline__ void scan_affine(int k, int ch, int& ps0, int& sk){
  int l0 = ch*TS;
  if (k == 0){ ps0 = l0; sk = 1; }
  else if (k == 1){ ps0 = ((l0 & 63) << 6) | (l0 >> 6); sk = 64; }
  else if (k == 2){ ps0 = (LL-1) - l0; sk = -1; }
  else { int m0 = (LL-1) - l0; ps0 = ((m0 & 63) << 6) | (m0 >> 6); sk = -64; }
}

// ---------- P1: local scans; stores hp + cumA; layout [bk][ch][n][c] ----------
__global__ void k_p1(const float* __restrict__ xi_t, const float* __restrict__ xdbl,
                     const float* __restrict__ dtpw, const float* __restrict__ dtpb,
                     const float* __restrict__ alog,
                     float* __restrict__ cumA, float* __restrict__ hp){
  int idx = blockIdx.x*256 + threadIdx.x;
  if (idx >= BB*KD*NCH*DIC) return;
  int b,k,ch,c; scan_decode(idx,b,k,ch,c);
  float Arow[NS];
  #pragma unroll
  for (int n=0;n<NS;++n) Arow[n] = -__expf(alog[(k*DIC+c)*NS+n]) * L2E;
  float4 wdt = *(const float4*)(dtpw + (k*DIC+c)*RD);
  float bdt = dtpb[k*DIC+c];
  int ps0, sk; scan_affine(k, ch, ps0, sk);
  const float* row = xdbl + (size_t)(b*KD+k)*LL*20 + (size_t)ps0*20;
  const float* up  = xi_t + (size_t)b*LL*DIC + c + (size_t)ps0*DIC;
  long rstep = (long)sk*20;
  long ustep = (long)sk*DIC;
  float h[NS];
  #pragma unroll
  for (int n=0;n<NS;++n) h[n]=0.f;
  float sumd = 0.f;
  #pragma unroll 4
  for (int t=0; t<TS; ++t){
    float4 q0 = *(const float4*)(row);
    float4 q1 = *(const float4*)(row+4);
    float4 q2 = *(const float4*)(row+8);
    float u = *up;
    float dt = bdt + q0.x*wdt.x + q0.y*wdt.y + q0.z*wdt.z + q0.w*wdt.w;
    dt = softplusf_(dt);
    sumd += dt;
    float du = dt*u;
    float Bv[NS] = {q1.x,q1.y,q1.z,q1.w,q2.x,q2.y,q2.z,q2.w};
    #pragma unroll
    for (int n=0;n<NS;++n)
      h[n] = h[n]*exp2f(dt*Arow[n]) + du*Bv[n];
    row += rstep; up += ustep;
  }
  size_t base = ((size_t)((b*KD+k)*NCH + ch)*NS)*DIC + c;
  #pragma unroll
  for (int n=0;n<NS;++n) hp[base + n*DIC] = h[n];
  #pragma unroll
  for (int n=0;n<NS;++n) cumA[base + n*DIC] = exp2f(sumd*Arow[n]);
}

// ---------- P2: prefix; zeroes cumA (=y_t) and gnstats ----------
__global__ void k_p2(float* __restrict__ cumA, float* __restrict__ hp,
                     float* __restrict__ gnstats){
  if (blockIdx.x == 0 && threadIdx.x < 2*BB*GRP) gnstats[threadIdx.x] = 0.f;
  int idx = blockIdx.x*256 + threadIdx.x;
  if (idx >= BB*KD*NS*DIC) return;
  int c = idx % DIC; int n = (idx/DIC) % NS; int bk = idx/(DIC*NS);
  float h = 0.f;
  #pragma unroll 8
  for (int ch=0; ch<NCH; ++ch){
    size_t base = ((size_t)(bk*NCH+ch)*NS + n)*DIC + c;
    float a = cumA[base];
    float pp = hp[base];
    cumA[base] = 0.f;
    hp[base] = h;
    h = a*h + pp;
  }
}

// ---------- P3: replay chunks (one direction/thread), atomic accumulate into y_t ----------
__global__ void k_p3(const float* __restrict__ xi_t, const float* __restrict__ xdbl,
                     const float* __restrict__ dtpw, const float* __restrict__ dtpb,
                     const float* __restrict__ alog, const float* __restrict__ Dsv,
                     const float* __restrict__ hin, float* __restrict__ y_t){
  int idx = blockIdx.x*256 + threadIdx.x;
  if (idx >= BB*KD*NCH*DIC) return;
  int b,k,ch,c; scan_decode(idx,b,k,ch,c);
  float Arow[NS];
  #pragma unroll
  for (int n=0;n<NS;++n) Arow[n] = -__expf(alog[(k*DIC+c)*NS+n]) * L2E;
  float4 wdt = *(const float4*)(dtpw + (k*DIC+c)*RD);
  float bdt = dtpb[k*DIC+c];
  float Dv = Dsv[k*DIC+c];
  int ps0, sk; scan_affine(k, ch, ps0, sk);
  const float* row = xdbl + (size_t)(b*KD+k)*LL*20 + (size_t)ps0*20;
  const float* up  = xi_t + (size_t)b*LL*DIC + c + (size_t)ps0*DIC;
  float* yp        = y_t  + (size_t)b*LL*DIC + c + (size_t)ps0*DIC;
  long rstep = (long)sk*20;
  long ustep = (long)sk*DIC;
  float h[NS];
  size_t base = ((size_t)((b*KD+k)*NCH + ch)*NS)*DIC + c;
  #pragma unroll
  for (int n=0;n<NS;++n) h[n] = hin[base + n*DIC];
  #pragma unroll 4
  for (int t=0; t<TS; ++t){
    float4 q0 = *(const float4*)(row);
    float4 q1 = *(const float4*)(row+4);
    float4 q2 = *(const float4*)(row+8);
    float4 q3 = *(const float4*)(row+12);
    float4 q4 = *(const float4*)(row+16);
    float u = *up;
    float dt = bdt + q0.x*wdt.x + q0.y*wdt.y + q0.z*wdt.z + q0.w*wdt.w;
    dt = softplusf_(dt);
    float du = dt*u;
    float Bv[NS] = {q1.x,q1.y,q1.z,q1.w,q2.x,q2.y,q2.z,q2.w};
    float Cv[NS] = {q3.x,q3.y,q3.z,q3.w,q4.x,q4.y,q4.z,q4.w};
    float y = 0.f;
    #pragma unroll
    for (int n=0;n<NS;++n){
      h[n] = h[n]*exp2f(dt*Arow[n]) + du*Bv[n];
      y += h[n]*Cv[n];
    }
    y += u*Dv;
    atomicAdd(yp, y);
    row += rstep; up += ustep; yp += ustep;
  }
}

// ---------- LN over c per pixel (wave-per-pixel), *ong+onb, *silu(z); also zeroes x ----------
__global__ void k_lnz(float* __restrict__ y_t, const float* __restrict__ z_t,
                      const float* __restrict__ ong, const float* __restrict__ onb,
                      float* __restrict__ xzero){
  int gid = blockIdx.x*256 + threadIdx.x;
  // zero x (dead between xz and oproj) for oproj's atomic partials
  xzero[gid] = 0.f;
  if (gid < (int)(BB*DMC*LL - BB*LL*64)) xzero[gid + BB*LL*64] = 0.f;
  int wid = gid >> 6;
  int lane = gid & 63;
  if (wid >= BB*LL) return;
  size_t rb = (size_t)wid * DIC;
  float v0 = y_t[rb + lane];
  float v1 = y_t[rb + 64 + lane];
  float v2 = (lane < 16) ? y_t[rb + 128 + lane] : 0.f;
  float s = v0 + v1 + v2;
  float q = v0*v0 + v1*v1 + v2*v2;
  #pragma unroll
  for (int o=32; o>0; o>>=1){ s += __shfl_xor(s,o,64); q += __shfl_xor(q,o,64); }
  float mu = s*(1.f/DIC);
  float var = q*(1.f/DIC) - mu*mu;
  float rs = rsqrtf(var + 1e-5f);
  float z0 = z_t[rb + lane];
  y_t[rb + lane] = ((v0-mu)*rs*ong[lane] + onb[lane]) * siluf_(z0);
  float z1 = z_t[rb + 64 + lane];
  y_t[rb + 64 + lane] = ((v1-mu)*rs*ong[64+lane] + onb[64+lane]) * siluf_(z1);
  if (lane < 16){
    float z2 = z_t[rb + 128 + lane];
    y_t[rb + 128 + lane] = ((v2-mu)*rs*ong[128+lane] + onb[128+lane]) * siluf_(z2);
  }
}

// ---------- out-proj matmul, LDS-staged, d-split x2, atomic partials into x ----------
__global__ void k_oproj(const float* __restrict__ yn, const float* __restrict__ opw,
                        float* __restrict__ xout){
  __shared__ float ly[72*65];
  int bid = blockIdx.x;            // BB * 64 tiles * 2 dhalves
  int dhalf = bid & 1; int r = bid >> 1;
  int tile = r & 63; int b = r >> 6;
  int pstart = tile*64;
  const float* src = yn + ((size_t)b*LL + pstart)*DIC + dhalf*72;
  for (int i = threadIdx.x; i < 64*72; i += 512){
    int px = i / 72; int d = i - px*72;
    ly[d*65 + px] = src[(size_t)px*DIC + d];
  }
  __syncthreads();
  int px = threadIdx.x & 63;
  int ocg = __builtin_amdgcn_readfirstlane(threadIdx.x >> 6);  // 0..7 wave-uniform
  float acc[9];
  #pragma unroll
  for (int j=0;j<9;++j) acc[j]=0.f;
  const float* wb = opw + (size_t)ocg*9*DIC + dhalf*72;
  #pragma unroll 4
  for (int d=0; d<72; ++d){
    float a = ly[d*65 + px];
    #pragma unroll
    for (int j=0;j<9;++j) acc[j] += a * wb[(size_t)j*DIC + d];
  }
  #pragma unroll
  for (int j=0;j<9;++j)
    atomicAdd(xout + ((size_t)(b*DMC + ocg*9 + j)<<12) + pstart + px, acc[j]);
}

// ---------- groupnorm stats: partial sums -> atomic (sum, sumsq) per (b,group) ----------
__global__ void k_gnA(const float* __restrict__ x, float* __restrict__ stats){
  __shared__ float s1[256], s2[256];
  int bid = blockIdx.x;    // BB*GRP*16
  int t = bid & 15; int r = bid >> 4; int gr = r % GRP; int b = r / GRP;
  float ls=0.f, lq=0.f;
  #pragma unroll
  for (int it=0; it<6; ++it){
    int i = t*1536 + it*256 + threadIdx.x;   // i in [0, 24576)
    int c = gr*6 + (i>>12); int p = i & 4095;
    float v = x[((size_t)(b*DMC+c)<<12)+p];
    ls += v; lq += v*v;
  }
  s1[threadIdx.x]=ls; s2[threadIdx.x]=lq; __syncthreads();
  for (int s=128; s>0; s>>=1){
    if (threadIdx.x < s){ s1[threadIdx.x]+=s1[threadIdx.x+s]; s2[threadIdx.x]+=s2[threadIdx.x+s]; }
    __syncthreads();
  }
  if (threadIdx.x == 0){
    atomicAdd(stats + (b*GRP+gr)*2,     s1[0]);
    atomicAdd(stats + (b*GRP+gr)*2 + 1, s2[0]);
  }
}

// ---------- dense1: l1( gn(x) ), GN A/B computed in-block ----------
__global__ void k_dense1(const float* __restrict__ xin, const float* __restrict__ gnstats,
                         const float* __restrict__ gng, const float* __restrict__ gnb,
                         const float* __restrict__ w, const float* __restrict__ bias,
                         float* __restrict__ xout){
  __shared__ float As[DMC], Bs[DMC];
  int bid = blockIdx.x;
  int t = bid & 15; int r = bid >> 4; int eg = r % 18; int b = r / 18;
  if (threadIdx.x < DMC){
    int c = threadIdx.x; int gr = c/6;
    float s = gnstats[(b*GRP+gr)*2];
    float q = gnstats[(b*GRP+gr)*2 + 1];
    const float inv = 1.f/(6.f*LL);
    float mu = s*inv;
    float var = q*inv - mu*mu;
    float rs = rsqrtf(var + 1e-5f);
    float A = rs*gng[c];
    As[c] = A;
    Bs[c] = gnb[c] - mu*A;
  }
  __syncthreads();
  int p = t*256 + threadIdx.x;
  float acc[4];
  #pragma unroll
  for (int j=0;j<4;++j) acc[j] = bias[eg*4+j];
  for (int c0=0; c0<DMC; c0+=4){
    float a[4];
    #pragma unroll
    for (int q=0;q<4;++q){
      float v = xin[((size_t)(b*DMC+c0+q)<<12)+p];
      a[q] = v*As[c0+q] + Bs[c0+q];
    }
    #pragma unroll
    for (int j=0;j<4;++j){
      float4 w0 = *(const float4*)(w + (eg*4+j)*DMC + c0);
      acc[j] += a[0]*w0.x + a[1]*w0.y + a[2]*w0.z + a[3]*w0.w;
    }
  }
  #pragma unroll
  for (int j=0;j<4;++j)
    xout[((size_t)(b*DMC+eg*4+j)<<12)+p] = acc[j];
}

// ---------- dense2: l2( lrelu(tmp) ) ----------
__global__ void k_dense2(const float* __restrict__ xin, const float* __restrict__ w,
                         const float* __restrict__ bias, float* __restrict__ xout,
                         float* __restrict__ pad_out){
  int bid = blockIdx.x;
  int t = bid & 15; int r = bid >> 4; int eg = r % 18; int b = r / 18;
  int p = t*256 + threadIdx.x;
  float acc[4];
  #pragma unroll
  for (int j=0;j<4;++j) acc[j] = bias[eg*4+j];
  for (int c0=0; c0<DMC; c0+=4){
    float a[4];
    #pragma unroll
    for (int q=0;q<4;++q){
      float v = xin[((size_t)(b*DMC+c0+q)<<12)+p];
      a[q] = v >= 0.f ? v : 0.04f*v;
    }
    #pragma unroll
    for (int j=0;j<4;++j){
      float4 w0 = *(const float4*)(w + (eg*4+j)*DMC + c0);
      acc[j] += a[0]*w0.x + a[1]*w0.y + a[2]*w0.z + a[3]*w0.w;
    }
  }
  int pb = padidx(p);
  #pragma unroll
  for (int j=0;j<4;++j){
    xout[((size_t)(b*DMC+eg*4+j)<<12)+p] = acc[j];
    if (pad_out) pad_out[(size_t)(b*DMC+eg*4+j)*PPN + pb] = acc[j];
  }
}

// ---------- shrink conv pass A ----------
__global__ void k_shrinkA(const float* __restrict__ x_pad, const float* __restrict__ w,
                          float* __restrict__ pacc){
  int bid = blockIdx.x;
  int t = bid & 15; int r = bid >> 4; int icg = r % 24; int b = r / 24;
  int p = t*256 + threadIdx.x;
  int pb = padidx(p);
  float acc[6] = {0.f,0.f,0.f,0.f,0.f,0.f};
  const float* ipb = x_pad + (size_t)b*DMC*PPN + pb;
  #pragma unroll
  for (int ii=0; ii<3; ++ii){
    int ic = icg*3 + ii;
    const float* ip = ipb + (size_t)ic*PPN;
    float a[9]; LOAD9(ip, a);
    #pragma unroll
    for (int o=0;o<6;++o){
      const float* wp = w + (o*DMC+ic)*9;
      float s = 0.f;
      #pragma unroll
      for (int q=0;q<9;++q) s += a[q]*wp[q];
      acc[o] += s;
    }
  }
  #pragma unroll
  for (int o=0;o<6;++o)
    atomicAdd(pacc + ((size_t)(b*CI+o)<<12)+p, acc[o]);
}

// ---------- shrink pass B ----------
__global__ void k_sig(const float* __restrict__ pacc, const float* __restrict__ bias,
                      float* __restrict__ out){
  int idx = blockIdx.x*256 + threadIdx.x;
  if (idx >= BB*CI*LL) return;
  int o = (idx>>12) % CI;
  out[idx] = sigmoidf_(pacc[idx] + bias[o]);
}

extern "C" void kernel_launch(void* const* d_in, const int* in_sizes, int n_in,
                              void* d_out, int out_size, void* d_ws, size_t ws_size,
                              hipStream_t stream){
  const float* image = (const float*)d_in[0];
  const float* cb_w1 = (const float*)d_in[1];
  const float* cb_b1 = (const float*)d_in[2];
  const float* cb_w2 = (const float*)d_in[3];
  const float* cb_b2 = (const float*)d_in[4];
  const float* cb_ws = (const float*)d_in[5];
  const float* cb_bs = (const float*)d_in[6];
  const float* in_w  = (const float*)d_in[7];
  const float* dw_w  = (const float*)d_in[8];
  const float* dw_b  = (const float*)d_in[9];
  const float* xp_w  = (const float*)d_in[10];
  const float* dtp_w = (const float*)d_in[11];
  const float* dtp_b = (const float*)d_in[12];
  const float* A_logs= (const float*)d_in[13];
  const float* Ds    = (const float*)d_in[14];
  const float* ong   = (const float*)d_in[15];
  const float* onb   = (const float*)d_in[16];
  const float* op_w  = (const float*)d_in[17];
  const float* gn_g  = (const float*)d_in[18];
  const float* gn_b  = (const float*)d_in[19];
  const float* l1_w  = (const float*)d_in[20];
  const float* l1_b  = (const float*)d_in[21];
  const float* l2_w  = (const float*)d_in[22];
  const float* l2_b  = (const float*)d_in[23];
  const float* sh_w  = (const float*)d_in[24];
  const float* sh_b  = (const float*)d_in[25];

  const size_t SZ_X  = (size_t)BB*DMC*LL;
  const size_t SZ_C  = (size_t)BB*DIC*LL;
  const size_t SZ_XD = (size_t)BB*KD*20*LL;
  const size_t SZ_HP = (size_t)BB*KD*NCH*NS*DIC;
  const size_t SZ_IP = (size_t)BB*CI*PPN;
  const size_t SZ_TP = (size_t)BB*DMC*PPN;
  const size_t SZ_ZP = (size_t)BB*DIC*PPN;

  float* ws = (float*)d_ws;
  size_t off = 0;
  float* x     = ws + off; off += SZ_X;
  float* tmp   = ws + off; off += SZ_X;
  float* z_t   = ws + off; off += SZ_C;
  float* xi_t  = ws + off; off += SZ_C;
  float* xdbl  = ws + off; off += SZ_XD;
  float* cumA  = ws + off; off += SZ_HP;  // aliased with y_t
  float* hp    = ws + off; off += SZ_HP;
  float* pads  = ws + off;
  float* img_pad = pads;
  float* tmp_pad = img_pad + SZ_IP;
  float* xz_pad  = tmp_pad + SZ_TP;
  off += SZ_IP + SZ_TP + SZ_ZP;
  float* gnstats = ws + off; off += 2*BB*GRP;
  if (ws_size < off*sizeof(float)) return;
  float* y_t = cumA;

  dim3 blk(256);
  const int NPLANES = BB*CI + BB*DMC + BB*DIC;

  k_prep<<<dim3(NPLANES + BB*CI*16), blk, 0, stream>>>(image, pads, img_pad, NPLANES);
  k_conv1<<<dim3(BB*DMC*4), blk, 0, stream>>>(img_pad, cb_w1, cb_b1, tmp_pad);
  k_conv2init<<<dim3(BB*18*16), blk, 0, stream>>>(image, cb_b2, cb_ws, cb_bs, x);
  k_conv2<<<dim3(BB*2*18*16), blk, 0, stream>>>(tmp_pad, cb_w2, x);

  for (int i=0; i<NLAYER; ++i){
    const float* in_w_i  = in_w  + (size_t)i*2*DIC*DMC;
    const float* dw_w_i  = dw_w  + (size_t)i*DIC*9;
    const float* dw_b_i  = dw_b  + (size_t)i*DIC;
    const float* xp_w_i  = xp_w  + (size_t)i*KD*20*DIC;
    const float* dtp_w_i = dtp_w + (size_t)i*KD*DIC*RD;
    const float* dtp_b_i = dtp_b + (size_t)i*KD*DIC;
    const float* alog_i  = A_logs+ (size_t)i*KD*DIC*NS;
    const float* Ds_i    = Ds    + (size_t)i*KD*DIC;
    const float* ong_i   = ong   + (size_t)i*DIC;
    const float* onb_i   = onb   + (size_t)i*DIC;
    const float* op_w_i  = op_w  + (size_t)i*DMC*DIC;
    const float* gn_g_i  = gn_g  + (size_t)i*DMC;
    const float* gn_b_i  = gn_b  + (size_t)i*DMC;
    const float* l1_w_i  = l1_w  + (size_t)i*DMC*DMC;
    const float* l1_b_i  = l1_b  + (size_t)i*DMC;
    const float* l2_w_i  = l2_w  + (size_t)i*DMC*DMC;
    const float* l2_b_i  = l2_b  + (size_t)i*DMC;

    k_xz  <<<dim3(BB*36*16), blk, 0, stream>>>(x, in_w_i, xz_pad, z_t, (i==0)?1:0);
    k_dw  <<<dim3(BB*DIC*4), blk, 0, stream>>>(xz_pad, dw_w_i, dw_b_i, xi_t);
    k_xdbl<<<dim3(BB*4*KD*16), blk, 0, stream>>>(xi_t, xp_w_i, xdbl);
    k_p1  <<<dim3(BB*KD*NCH*DIC/256), blk, 0, stream>>>(xi_t, xdbl, dtp_w_i, dtp_b_i, alog_i, cumA, hp);
    k_p2  <<<dim3(BB*KD*NS*DIC/256), blk, 0, stream>>>(cumA, hp, gnstats);
    k_p3  <<<dim3(BB*KD*NCH*DIC/256), blk, 0, stream>>>(xi_t, xdbl, dtp_w_i, dtp_b_i, alog_i, Ds_i, hp, y_t);
    k_lnz <<<dim3(BB*LL/4), blk, 0, stream>>>(y_t, z_t, ong_i, onb_i, x);
    k_oproj<<<dim3(BB*64*2), dim3(512), 0, stream>>>(y_t, op_w_i, x);
    k_gnA <<<dim3(BB*GRP*16), blk, 0, stream>>>(x, gnstats);
    k_dense1<<<dim3(BB*18*16), blk, 0, stream>>>(x, gnstats, gn_g_i, gn_b_i, l1_w_i, l1_b_i, tmp);
    k_dense2<<<dim3(BB*18*16), blk, 0, stream>>>(tmp, l2_w_i, l2_b_i, x,
                                                 (i==NLAYER-1) ? tmp_pad : (float*)nullptr);
  }

  hipMemsetAsync(tmp, 0, (size_t)BB*CI*LL*sizeof(float), stream);
  k_shrinkA<<<dim3(BB*24*16), blk, 0, stream>>>(tmp_pad, sh_w, tmp);
  k_sig<<<dim3((BB*CI*LL+255)/256), blk, 0, stream>>>(tmp, sh_b, (float*)d_out);
}